// Round 1
// baseline (1460.390 us; speedup 1.0000x reference)
//
#include <hip/hip_runtime.h>
#include <math.h>

#define H 128
#define FCD 256

// ---------------- CSR build ----------------
__global__ void k_deg(const int* __restrict__ ei, int E, int N, int* __restrict__ deg){
  int j = blockIdx.x*256 + threadIdx.x;
  if (j >= E+N) return;
  int dst = (j < E) ? ei[E+j] : (j-E);
  atomicAdd(&deg[dst], 1);
}

__global__ void k_scan(const int* __restrict__ deg, int N,
                       int* __restrict__ row_ptr, int* __restrict__ nxt){
  __shared__ int sm[1024];
  __shared__ int carry;
  int t = threadIdx.x;
  if (t==0) carry = 0;
  __syncthreads();
  for (int base=0; base<N; base+=1024){
    int i = base + t;
    int v = (i<N) ? deg[i] : 0;
    sm[t] = v;
    __syncthreads();
    for (int off=1; off<1024; off<<=1){
      int add = (t>=off) ? sm[t-off] : 0;
      __syncthreads();
      sm[t] += add;
      __syncthreads();
    }
    int incl = sm[t];
    if (i<N){ int rp = carry + incl - v; row_ptr[i]=rp; nxt[i]=rp; }
    __syncthreads();
    if (t==1023) carry += incl;
    __syncthreads();
  }
  if (t==0) row_ptr[N] = carry;
}

__global__ void k_scatter(const int* __restrict__ ei, int E, int N,
                          int* __restrict__ nxt, int* __restrict__ csr_src){
  int j = blockIdx.x*256 + threadIdx.x;
  if (j >= E+N) return;
  int src, dst;
  if (j < E){ src = ei[j]; dst = ei[E+j]; } else { src = j-E; dst = j-E; }
  int pos = atomicAdd(&nxt[dst], 1);
  csr_src[pos] = src;
}

// ---------------- dense: out[n,128] = h[n,K] @ W[K,128] + bias ----------------
template<int K, int NT>
__global__ void k_gemm(const float* __restrict__ h, const float* __restrict__ W,
                       const float* __restrict__ bias, float* __restrict__ out, int n){
  int col = threadIdx.x;            // 0..127
  int n0 = blockIdx.x*NT;
  const float* hp[NT];
  #pragma unroll
  for (int t=0;t<NT;t++){
    int node = n0+t; if (node >= n) node = n-1;
    hp[t] = h + (size_t)node*K;
  }
  float b = bias[col];
  float acc[NT];
  #pragma unroll
  for (int t=0;t<NT;t++) acc[t]=b;
  #pragma unroll 4
  for (int k=0;k<K;k++){
    float w = W[k*H + col];
    #pragma unroll
    for (int t=0;t<NT;t++) acc[t] = fmaf(hp[t][k], w, acc[t]);
  }
  #pragma unroll
  for (int t=0;t<NT;t++){
    int node=n0+t;
    if (node<n) out[(size_t)node*H + col] = acc[t];
  }
}

// ---------------- GATv2 per-dst online-softmax aggregate + ELU ----------------
__global__ void k_gat(const float* __restrict__ xl, const float* __restrict__ xr,
                      const float* __restrict__ att, const float* __restrict__ bo,
                      const int* __restrict__ row_ptr, const int* __restrict__ csr_src,
                      float* __restrict__ hout, int n){
  int lane = threadIdx.x & 63;
  int node = (blockIdx.x*blockDim.x + threadIdx.x) >> 6;
  if (node >= n) return;
  int f = lane*2;
  float2 xrv = *(const float2*)(xr + (size_t)node*H + f);
  float2 av  = *(const float2*)(att + f);
  float mmax = -INFINITY, denom = 0.f;
  float accx = 0.f, accy = 0.f;
  int beg = row_ptr[node], end = row_ptr[node+1];
  for (int j=beg; j<end; j++){
    int s = csr_src[j];
    float2 xlv = *(const float2*)(xl + (size_t)s*H + f);
    float mx = xlv.x + xrv.x; mx = mx > 0.f ? mx : 0.2f*mx;
    float my = xlv.y + xrv.y; my = my > 0.f ? my : 0.2f*my;
    float part = mx*av.x + my*av.y;
    #pragma unroll
    for (int off=32; off; off>>=1) part += __shfl_xor(part, off);
    float e = part;                        // full dot, all lanes
    if (e > mmax){
      float sc = __expf(mmax - e);         // first iter: exp(-inf)=0
      accx *= sc; accy *= sc; denom *= sc;
      mmax = e;
    }
    float w = __expf(e - mmax);
    denom += w;
    accx += w*xlv.x; accy += w*xlv.y;
  }
  float inv = 1.f/denom;
  float2 bov = *(const float2*)(bo + f);
  float ox = accx*inv + bov.x;
  float oy = accy*inv + bov.y;
  ox = ox > 0.f ? ox : expm1f(ox);         // ELU fused
  oy = oy > 0.f ? oy : expm1f(oy);
  float2 o; o.x = ox; o.y = oy;
  *(float2*)(hout + (size_t)node*H + f) = o;
}

// ---------------- global mean pool (atomics) ----------------
__global__ void k_pool(const float* __restrict__ h, const int* __restrict__ batch,
                       float* __restrict__ sums, float* __restrict__ cnt, int n){
  int idx = blockIdx.x*blockDim.x + threadIdx.x;
  int node = idx >> 6, lane = idx & 63;
  if (node >= n) return;
  int b = batch[node];
  int f = lane*2;
  float2 v = *(const float2*)(h + (size_t)node*H + f);
  atomicAdd(&sums[b*H+f],   v.x);
  atomicAdd(&sums[b*H+f+1], v.y);
  if (lane==0) atomicAdd(&cnt[b], 1.0f);
}

// ---------------- fused MLP head + log_softmax ----------------
__global__ void k_fc(const float* __restrict__ sums, const float* __restrict__ cnt,
                     const float* __restrict__ W1, const float* __restrict__ b1,
                     const float* __restrict__ W2, const float* __restrict__ b2,
                     float* __restrict__ out){
  __shared__ float g[H];
  __shared__ float z[FCD];
  int gi = blockIdx.x;
  int t = threadIdx.x;     // 0..255
  float c = cnt[gi]; if (c < 1.f) c = 1.f;
  if (t < H) g[t] = sums[gi*H+t] / c;
  __syncthreads();
  float acc = b1[t];
  for (int k=0;k<H;k++) acc = fmaf(g[k], W1[k*FCD+t], acc);
  z[t] = acc > 0.f ? acc : 0.f;
  __syncthreads();
  if (t < 2){
    float l = b2[t];
    for (int k=0;k<FCD;k++) l = fmaf(z[k], W2[k*2+t], l);
    g[t] = l;
  }
  __syncthreads();
  if (t < 2){
    float l0 = g[0], l1 = g[1];
    float mx = fmaxf(l0,l1);
    float lse = mx + logf(__expf(l0-mx) + __expf(l1-mx));
    out[gi*2+t] = g[t] - lse;
  }
}

extern "C" void kernel_launch(void* const* d_in, const int* in_sizes, int n_in,
                              void* d_out, int out_size, void* d_ws, size_t ws_size,
                              hipStream_t stream) {
  const float* x     = (const float*)d_in[0];
  const int*   ei    = (const int*)  d_in[1];
  const int*   batch = (const int*)  d_in[2];
  const float* Wl[3]  = {(const float*)d_in[3],  (const float*)d_in[9],  (const float*)d_in[15]};
  const float* bl[3]  = {(const float*)d_in[4],  (const float*)d_in[10], (const float*)d_in[16]};
  const float* Wr[3]  = {(const float*)d_in[5],  (const float*)d_in[11], (const float*)d_in[17]};
  const float* br[3]  = {(const float*)d_in[6],  (const float*)d_in[12], (const float*)d_in[18]};
  const float* att[3] = {(const float*)d_in[7],  (const float*)d_in[13], (const float*)d_in[19]};
  const float* bo[3]  = {(const float*)d_in[8],  (const float*)d_in[14], (const float*)d_in[20]};
  const float* fc1W = (const float*)d_in[21];
  const float* fc1b = (const float*)d_in[22];
  const float* fc2W = (const float*)d_in[23];
  const float* fc2b = (const float*)d_in[24];

  const int N  = in_sizes[2];
  const int E  = in_sizes[1]/2;
  const int Et = E + N;
  const int G  = out_size/2;

  char* p = (char*)d_ws;
  auto alloc = [&](size_t bytes)->void*{
    void* r = (void*)p; p += (bytes + 255) & ~(size_t)255; return r;
  };
  int*   deg     = (int*)  alloc((size_t)N*4);
  int*   row_ptr = (int*)  alloc((size_t)(N+1)*4);
  int*   nxt     = (int*)  alloc((size_t)N*4);
  int*   csr     = (int*)  alloc((size_t)Et*4);
  float* xl      = (float*)alloc((size_t)N*H*4);
  float* xr      = (float*)alloc((size_t)N*H*4);
  float* hbuf    = (float*)alloc((size_t)N*H*4);
  float* sums    = (float*)alloc((size_t)G*H*4);
  float* cnt     = (float*)alloc((size_t)G*4);

  // CSR by dst (edge list static across layers)
  hipMemsetAsync(deg, 0, (size_t)N*4, stream);
  k_deg    <<<(Et+255)/256, 256, 0, stream>>>(ei, E, N, deg);
  k_scan   <<<1, 1024, 0, stream>>>(deg, N, row_ptr, nxt);
  k_scatter<<<(Et+255)/256, 256, 0, stream>>>(ei, E, N, nxt, csr);

  const int gemmGrid = (N + 7)/8;
  const int gatGrid  = ((size_t)N*64 + 255)/256;

  // layer 0 (K=7)
  k_gemm<7,8><<<gemmGrid, 128, 0, stream>>>(x, Wl[0], bl[0], xl, N);
  k_gemm<7,8><<<gemmGrid, 128, 0, stream>>>(x, Wr[0], br[0], xr, N);
  k_gat<<<gatGrid, 256, 0, stream>>>(xl, xr, att[0], bo[0], row_ptr, csr, hbuf, N);
  // layer 1
  k_gemm<128,8><<<gemmGrid, 128, 0, stream>>>(hbuf, Wl[1], bl[1], xl, N);
  k_gemm<128,8><<<gemmGrid, 128, 0, stream>>>(hbuf, Wr[1], br[1], xr, N);
  k_gat<<<gatGrid, 256, 0, stream>>>(xl, xr, att[1], bo[1], row_ptr, csr, hbuf, N);
  // layer 2
  k_gemm<128,8><<<gemmGrid, 128, 0, stream>>>(hbuf, Wl[2], bl[2], xl, N);
  k_gemm<128,8><<<gemmGrid, 128, 0, stream>>>(hbuf, Wr[2], br[2], xr, N);
  k_gat<<<gatGrid, 256, 0, stream>>>(xl, xr, att[2], bo[2], row_ptr, csr, hbuf, N);

  // pool + head
  hipMemsetAsync(sums, 0, (size_t)G*H*4, stream);
  hipMemsetAsync(cnt,  0, (size_t)G*4,   stream);
  k_pool<<<gatGrid, 256, 0, stream>>>(hbuf, batch, sums, cnt, N);
  k_fc<<<G, 256, 0, stream>>>(sums, cnt, fc1W, fc1b, fc2W, fc2b, (float*)d_out);
}

// Round 2
// 942.545 us; speedup vs baseline: 1.5494x; 1.5494x over previous
//
#include <hip/hip_runtime.h>
#include <hip/hip_fp16.h>
#include <math.h>

#define H 128
#define FCD 256

// ---------------- CSR build ----------------
__global__ void k_deg(const int* __restrict__ ei, int E, int N, int* __restrict__ deg){
  int j = blockIdx.x*256 + threadIdx.x;
  if (j >= E+N) return;
  int dst = (j < E) ? ei[E+j] : (j-E);
  atomicAdd(&deg[dst], 1);
}

// single-block scan, wave-shuffle based (4 barriers per 1024-chunk)
__global__ void k_scan(const int* __restrict__ deg, int N,
                       int* __restrict__ row_ptr, int* __restrict__ nxt){
  __shared__ int wsum[16];
  __shared__ int carry_s;
  int t = threadIdx.x, lane = t & 63, w = t >> 6;
  if (t==0) carry_s = 0;
  __syncthreads();
  for (int base=0; base<N; base+=1024){
    int i = base + t;
    int v = (i<N) ? deg[i] : 0;
    int x = v;
    #pragma unroll
    for (int off=1; off<64; off<<=1){
      int y = __shfl_up(x, off);
      if (lane >= off) x += y;
    }
    if (lane==63) wsum[w] = x;
    __syncthreads();
    if (w==0 && lane<16){
      int s = wsum[lane];
      #pragma unroll
      for (int off=1; off<16; off<<=1){
        int y = __shfl_up(s, off);
        if (lane >= off) s += y;
      }
      wsum[lane] = s;
    }
    __syncthreads();
    int waveoff = (w==0) ? 0 : wsum[w-1];
    int incl = x + waveoff;
    int carry = carry_s;
    if (i<N){ int rp = carry + incl - v; row_ptr[i]=rp; nxt[i]=rp; }
    int tot = wsum[15];
    __syncthreads();
    if (t==0) carry_s = carry + tot;
    __syncthreads();
  }
  if (t==0) row_ptr[N] = carry_s;
}

__global__ void k_scatter(const int* __restrict__ ei, int E, int N,
                          int* __restrict__ nxt, int* __restrict__ csr_src){
  int j = blockIdx.x*256 + threadIdx.x;
  if (j >= E+N) return;
  int src, dst;
  if (j < E){ src = ei[j]; dst = ei[E+j]; } else { src = j-E; dst = j-E; }
  int pos = atomicAdd(&nxt[dst], 1);
  csr_src[pos] = src;
}

// ---------------- fused K=7 GEMM pair (layer 0): xl/xr fp16 out ----------------
__global__ void k_gemm7(const float* __restrict__ x,
                        const float* __restrict__ Wl, const float* __restrict__ bl,
                        const float* __restrict__ Wr, const float* __restrict__ br,
                        __half* __restrict__ xl, __half* __restrict__ xr, int n){
  int col = threadIdx.x;            // 0..127
  int n0 = blockIdx.x*8;
  float accl[8], accr[8];
  float bL = bl[col], bR = br[col];
  #pragma unroll
  for (int t=0;t<8;t++){ accl[t]=bL; accr[t]=bR; }
  #pragma unroll
  for (int k=0;k<7;k++){
    float wl = Wl[k*H + col];
    float wr = Wr[k*H + col];
    #pragma unroll
    for (int t=0;t<8;t++){
      int node = n0+t; if (node >= n) node = n-1;
      float hv = x[(size_t)node*7 + k];
      accl[t] = fmaf(hv, wl, accl[t]);
      accr[t] = fmaf(hv, wr, accr[t]);
    }
  }
  #pragma unroll
  for (int t=0;t<8;t++){
    int node = n0+t;
    if (node < n){
      xl[(size_t)node*H + col] = __float2half(accl[t]);
      xr[(size_t)node*H + col] = __float2half(accr[t]);
    }
  }
}

// ---------------- fused K=128 GEMM pair: h[n,128]@{Wl,Wr} -> xl,xr (fp16) ------
// 256 threads: 8 row-groups x 32 col-threads; 4 rows/thread, 4 cols/thread
__global__ void k_gemm2(const float* __restrict__ h,
                        const float* __restrict__ Wl, const float* __restrict__ bl,
                        const float* __restrict__ Wr, const float* __restrict__ br,
                        __half* __restrict__ xl, __half* __restrict__ xr, int n){
  int t = threadIdx.x;
  int cg = t & 31;            // column quad index
  int rg = t >> 5;            // 0..7
  int col = cg*4;
  int row0 = blockIdx.x*32 + rg*4;
  float4 blv = *(const float4*)(bl + col);
  float4 brv = *(const float4*)(br + col);
  float4 accl[4], accr[4];
  const float* hp[4];
  #pragma unroll
  for (int r=0;r<4;r++){
    accl[r]=blv; accr[r]=brv;
    int rr = row0+r; if (rr >= n) rr = n-1;
    hp[r] = h + (size_t)rr*H;
  }
  for (int k=0;k<H;k+=4){
    float4 hv[4];
    #pragma unroll
    for (int r=0;r<4;r++) hv[r] = *(const float4*)(hp[r]+k);
    #pragma unroll
    for (int i=0;i<4;i++){
      float4 wl = *(const float4*)(Wl + (size_t)(k+i)*H + col);
      float4 wr = *(const float4*)(Wr + (size_t)(k+i)*H + col);
      #pragma unroll
      for (int r=0;r<4;r++){
        float hk = (i==0)?hv[r].x:(i==1)?hv[r].y:(i==2)?hv[r].z:hv[r].w;
        accl[r].x = fmaf(hk, wl.x, accl[r].x);
        accl[r].y = fmaf(hk, wl.y, accl[r].y);
        accl[r].z = fmaf(hk, wl.z, accl[r].z);
        accl[r].w = fmaf(hk, wl.w, accl[r].w);
        accr[r].x = fmaf(hk, wr.x, accr[r].x);
        accr[r].y = fmaf(hk, wr.y, accr[r].y);
        accr[r].z = fmaf(hk, wr.z, accr[r].z);
        accr[r].w = fmaf(hk, wr.w, accr[r].w);
      }
    }
  }
  #pragma unroll
  for (int r=0;r<4;r++){
    int row = row0+r;
    if (row < n){
      size_t off = (size_t)row*H + col;
      *(__half2*)(xl+off)   = __floats2half2_rn(accl[r].x, accl[r].y);
      *(__half2*)(xl+off+2) = __floats2half2_rn(accl[r].z, accl[r].w);
      *(__half2*)(xr+off)   = __floats2half2_rn(accr[r].x, accr[r].y);
      *(__half2*)(xr+off+2) = __floats2half2_rn(accr[r].z, accr[r].w);
    }
  }
}

// ------------- GATv2 per-dst online-softmax aggregate + ELU (fp16 gather) -----
// POOL=1: fuse global_mean_pool accumulation (layer 3), no hout write.
template<int POOL>
__global__ void k_gat(const __half* __restrict__ xl, const __half* __restrict__ xr,
                      const float* __restrict__ att, const float* __restrict__ bo,
                      const int* __restrict__ row_ptr, const int* __restrict__ csr_src,
                      float* __restrict__ hout,
                      const int* __restrict__ batch, float* __restrict__ sums,
                      float* __restrict__ cnt, int n){
  int lane = threadIdx.x & 63;
  int node = (blockIdx.x*blockDim.x + threadIdx.x) >> 6;
  if (node >= n) return;
  node = __builtin_amdgcn_readfirstlane(node);   // wave-uniform -> scalar pipe
  int f = lane*2;
  float2 xrv = __half22float2(*(const __half2*)(xr + (size_t)node*H + f));
  float2 av  = *(const float2*)(att + f);
  float mmax = -INFINITY, denom = 0.f;
  float accx = 0.f, accy = 0.f;
  int beg = row_ptr[node], end = row_ptr[node+1];
  int j = beg;
  for (; j+3 < end; j += 4){
    int s[4]; float2 v[4]; float e[4];
    #pragma unroll
    for (int u=0;u<4;u++) s[u] = csr_src[j+u];
    #pragma unroll
    for (int u=0;u<4;u++)
      v[u] = __half22float2(*(const __half2*)(xl + (size_t)s[u]*H + f));
    #pragma unroll
    for (int u=0;u<4;u++){
      float mx = v[u].x + xrv.x; mx = mx > 0.f ? mx : 0.2f*mx;
      float my = v[u].y + xrv.y; my = my > 0.f ? my : 0.2f*my;
      e[u] = mx*av.x + my*av.y;
    }
    #pragma unroll
    for (int off=32; off; off>>=1){
      #pragma unroll
      for (int u=0;u<4;u++) e[u] += __shfl_xor(e[u], off);
    }
    float m4 = fmaxf(fmaxf(e[0],e[1]), fmaxf(e[2],e[3]));
    if (m4 > mmax){
      float sc = __expf(mmax - m4);
      accx *= sc; accy *= sc; denom *= sc;
      mmax = m4;
    }
    #pragma unroll
    for (int u=0;u<4;u++){
      float w = __expf(e[u] - mmax);
      denom += w;
      accx = fmaf(w, v[u].x, accx);
      accy = fmaf(w, v[u].y, accy);
    }
  }
  for (; j<end; j++){
    int s = csr_src[j];
    float2 v = __half22float2(*(const __half2*)(xl + (size_t)s*H + f));
    float mx = v.x + xrv.x; mx = mx > 0.f ? mx : 0.2f*mx;
    float my = v.y + xrv.y; my = my > 0.f ? my : 0.2f*my;
    float e = mx*av.x + my*av.y;
    #pragma unroll
    for (int off=32; off; off>>=1) e += __shfl_xor(e, off);
    if (e > mmax){
      float sc = __expf(mmax - e);
      accx *= sc; accy *= sc; denom *= sc;
      mmax = e;
    }
    float w = __expf(e - mmax);
    denom += w;
    accx = fmaf(w, v.x, accx);
    accy = fmaf(w, v.y, accy);
  }
  float inv = 1.f/denom;
  float2 bov = *(const float2*)(bo + f);
  float ox = accx*inv + bov.x;
  float oy = accy*inv + bov.y;
  ox = ox > 0.f ? ox : expm1f(ox);     // ELU fused
  oy = oy > 0.f ? oy : expm1f(oy);
  if (POOL){
    int b = batch[node];
    atomicAdd(&sums[b*H+f],   ox);
    atomicAdd(&sums[b*H+f+1], oy);
    if (lane==0) atomicAdd(&cnt[b], 1.0f);
  } else {
    float2 o; o.x = ox; o.y = oy;
    *(float2*)(hout + (size_t)node*H + f) = o;
  }
}

// ---------------- fused MLP head + log_softmax ----------------
__global__ void k_fc(const float* __restrict__ sums, const float* __restrict__ cnt,
                     const float* __restrict__ W1, const float* __restrict__ b1,
                     const float* __restrict__ W2, const float* __restrict__ b2,
                     float* __restrict__ out){
  __shared__ float g[H];
  __shared__ float z[FCD];
  int gi = blockIdx.x;
  int t = threadIdx.x;     // 0..255
  float c = cnt[gi]; if (c < 1.f) c = 1.f;
  if (t < H) g[t] = sums[gi*H+t] / c;
  __syncthreads();
  float acc = b1[t];
  for (int k=0;k<H;k++) acc = fmaf(g[k], W1[k*FCD+t], acc);
  z[t] = acc > 0.f ? acc : 0.f;
  __syncthreads();
  if (t < 2){
    float l = b2[t];
    for (int k=0;k<FCD;k++) l = fmaf(z[k], W2[k*2+t], l);
    g[t] = l;
  }
  __syncthreads();
  if (t < 2){
    float l0 = g[0], l1 = g[1];
    float mx = fmaxf(l0,l1);
    float lse = mx + logf(__expf(l0-mx) + __expf(l1-mx));
    out[gi*2+t] = g[t] - lse;
  }
}

extern "C" void kernel_launch(void* const* d_in, const int* in_sizes, int n_in,
                              void* d_out, int out_size, void* d_ws, size_t ws_size,
                              hipStream_t stream) {
  const float* x     = (const float*)d_in[0];
  const int*   ei    = (const int*)  d_in[1];
  const int*   batch = (const int*)  d_in[2];
  const float* Wl[3]  = {(const float*)d_in[3],  (const float*)d_in[9],  (const float*)d_in[15]};
  const float* bl[3]  = {(const float*)d_in[4],  (const float*)d_in[10], (const float*)d_in[16]};
  const float* Wr[3]  = {(const float*)d_in[5],  (const float*)d_in[11], (const float*)d_in[17]};
  const float* br[3]  = {(const float*)d_in[6],  (const float*)d_in[12], (const float*)d_in[18]};
  const float* att[3] = {(const float*)d_in[7],  (const float*)d_in[13], (const float*)d_in[19]};
  const float* bo[3]  = {(const float*)d_in[8],  (const float*)d_in[14], (const float*)d_in[20]};
  const float* fc1W = (const float*)d_in[21];
  const float* fc1b = (const float*)d_in[22];
  const float* fc2W = (const float*)d_in[23];
  const float* fc2b = (const float*)d_in[24];

  const int N  = in_sizes[2];
  const int E  = in_sizes[1]/2;
  const int Et = E + N;
  const int G  = out_size/2;

  char* p = (char*)d_ws;
  auto alloc = [&](size_t bytes)->void*{
    void* r = (void*)p; p += (bytes + 255) & ~(size_t)255; return r;
  };
  int*    deg     = (int*)   alloc((size_t)N*4);
  int*    row_ptr = (int*)   alloc((size_t)(N+1)*4);
  int*    nxt     = (int*)   alloc((size_t)N*4);
  int*    csr     = (int*)   alloc((size_t)Et*4);
  __half* xl      = (__half*)alloc((size_t)N*H*2);
  __half* xr      = (__half*)alloc((size_t)N*H*2);
  float*  hbuf    = (float*) alloc((size_t)N*H*4);
  float*  sums    = (float*) alloc((size_t)G*H*4);
  float*  cnt     = (float*) alloc((size_t)G*4);

  // CSR by dst (edge list static across layers)
  hipMemsetAsync(deg, 0, (size_t)N*4, stream);
  k_deg    <<<(Et+255)/256, 256, 0, stream>>>(ei, E, N, deg);
  k_scan   <<<1, 1024, 0, stream>>>(deg, N, row_ptr, nxt);
  k_scatter<<<(Et+255)/256, 256, 0, stream>>>(ei, E, N, nxt, csr);

  const int g7  = (N + 7)/8;
  const int g2  = (N + 31)/32;
  const int gg  = (int)(((size_t)N*64 + 255)/256);

  // zero pool buffers early (used by layer-3 fused gat)
  hipMemsetAsync(sums, 0, (size_t)G*H*4, stream);
  hipMemsetAsync(cnt,  0, (size_t)G*4,   stream);

  // layer 0 (K=7)
  k_gemm7<<<g7, 128, 0, stream>>>(x, Wl[0], bl[0], Wr[0], br[0], xl, xr, N);
  k_gat<0><<<gg, 256, 0, stream>>>(xl, xr, att[0], bo[0], row_ptr, csr, hbuf,
                                   batch, sums, cnt, N);
  // layer 1
  k_gemm2<<<g2, 256, 0, stream>>>(hbuf, Wl[1], bl[1], Wr[1], br[1], xl, xr, N);
  k_gat<0><<<gg, 256, 0, stream>>>(xl, xr, att[1], bo[1], row_ptr, csr, hbuf,
                                   batch, sums, cnt, N);
  // layer 2 (+fused mean-pool accumulate)
  k_gemm2<<<g2, 256, 0, stream>>>(hbuf, Wl[2], bl[2], Wr[2], br[2], xl, xr, N);
  k_gat<1><<<gg, 256, 0, stream>>>(xl, xr, att[2], bo[2], row_ptr, csr, hbuf,
                                   batch, sums, cnt, N);

  // head
  k_fc<<<G, 256, 0, stream>>>(sums, cnt, fc1W, fc1b, fc2W, fc2b, (float*)d_out);
}

// Round 3
// 861.272 us; speedup vs baseline: 1.6956x; 1.0944x over previous
//
#include <hip/hip_runtime.h>
#include <hip/hip_fp16.h>
#include <math.h>

#define H 128
#define FCD 256

typedef _Float16 half8 __attribute__((ext_vector_type(8)));
typedef float floatx4 __attribute__((ext_vector_type(4)));

// ---------------- DPP 16-lane (row) reduction: 4 VALU adds, no LDS pipe -------
template<int CTRL>
__device__ __forceinline__ float dppadd(float x){
  return x + __int_as_float(__builtin_amdgcn_update_dpp(
      0, __float_as_int(x), CTRL, 0xf, 0xf, true));
}
__device__ __forceinline__ float grp16_sum(float x){
  x = dppadd<0x128>(x);   // row_ror:8
  x = dppadd<0x124>(x);   // row_ror:4
  x = dppadd<0x122>(x);   // row_ror:2
  x = dppadd<0x121>(x);   // row_ror:1
  return x;
}

// ---------------- CSR build ----------------
__global__ void k_deg(const int* __restrict__ ei, int E, int N, int* __restrict__ deg){
  int j = blockIdx.x*256 + threadIdx.x;
  if (j >= E+N) return;
  int dst = (j < E) ? ei[E+j] : (j-E);
  atomicAdd(&deg[dst], 1);
}

// block sums (256/deg per block)
__global__ void k_scanA(const int* __restrict__ deg, int N, int* __restrict__ bsum){
  int t = threadIdx.x, lane = t & 63, w = t >> 6;
  int i = blockIdx.x*256 + t;
  int v = (i<N) ? deg[i] : 0;
  #pragma unroll
  for (int off=32; off; off>>=1) v += __shfl_xor(v, off);
  __shared__ int ws[4];
  if (lane==0) ws[w] = v;
  __syncthreads();
  if (t==0) bsum[blockIdx.x] = ws[0]+ws[1]+ws[2]+ws[3];
}

// exclusive scan of block sums (nb <= 256), single block
__global__ void k_scanB(int* __restrict__ bsum, int nb, int* __restrict__ totalp){
  int t = threadIdx.x, lane = t & 63, w = t >> 6;
  int v = (t<nb) ? bsum[t] : 0;
  int x = v;
  #pragma unroll
  for (int off=1; off<64; off<<=1){
    int y = __shfl_up(x, off);
    if (lane >= off) x += y;
  }
  __shared__ int ws[4];
  if (lane==63) ws[w] = x;
  __syncthreads();
  int woff = (w>0?ws[0]:0) + (w>1?ws[1]:0) + (w>2?ws[2]:0);
  int incl = x + woff;
  if (t<nb) bsum[t] = incl - v;         // exclusive
  if (t==255) *totalp = incl;           // grand total (v=0 past nb)
}

// per-block rescan + offset -> row_ptr, nxt
__global__ void k_scanC(const int* __restrict__ deg, const int* __restrict__ bsum, int N,
                        int* __restrict__ row_ptr, int* __restrict__ nxt){
  int t = threadIdx.x, lane = t & 63, w = t >> 6;
  int i = blockIdx.x*256 + t;
  int v = (i<N) ? deg[i] : 0;
  int x = v;
  #pragma unroll
  for (int off=1; off<64; off<<=1){
    int y = __shfl_up(x, off);
    if (lane >= off) x += y;
  }
  __shared__ int ws[4];
  if (lane==63) ws[w] = x;
  __syncthreads();
  int woff = (w>0?ws[0]:0) + (w>1?ws[1]:0) + (w>2?ws[2]:0);
  int excl = bsum[blockIdx.x] + woff + x - v;
  if (i<N){ row_ptr[i] = excl; nxt[i] = excl; }
}

__global__ void k_scatter(const int* __restrict__ ei, int E, int N,
                          int* __restrict__ nxt, int* __restrict__ csr_src){
  int j = blockIdx.x*256 + threadIdx.x;
  if (j >= E+N) return;
  int src, dst;
  if (j < E){ src = ei[j]; dst = ei[E+j]; } else { src = j-E; dst = j-E; }
  int pos = atomicAdd(&nxt[dst], 1);
  csr_src[pos] = src;
}

// ------------- weight prep: Wl/Wr (128x128 f32, k-major) -> Wt fp16 [L][n][k] --
__global__ void k_prep(const float* __restrict__ Wl1, const float* __restrict__ Wr1,
                       const float* __restrict__ Wl2, const float* __restrict__ Wr2,
                       _Float16* __restrict__ Wt){
  int idx = blockIdx.x*256 + threadIdx.x;   // 2*256*128 = 65536 total
  int L   = idx >> 15;
  int rem = idx & 32767;
  int nn  = rem >> 7;        // 0..255
  int k   = rem & 127;
  const float* W = (L==0) ? (nn<H?Wl1:Wr1) : (nn<H?Wl2:Wr2);
  Wt[idx] = (_Float16)W[k*H + (nn&127)];
}

// ---------------- layer-0 K=7 GEMM pair: x fp32 -> xl/xr fp16 ----------------
__global__ void k_gemm7(const float* __restrict__ x,
                        const float* __restrict__ Wl, const float* __restrict__ bl,
                        const float* __restrict__ Wr, const float* __restrict__ br,
                        __half* __restrict__ xl, __half* __restrict__ xr, int n){
  int col = threadIdx.x;            // 0..127
  int n0 = blockIdx.x*8;
  float accl[8], accr[8];
  float bL = bl[col], bR = br[col];
  #pragma unroll
  for (int t=0;t<8;t++){ accl[t]=bL; accr[t]=bR; }
  #pragma unroll
  for (int k=0;k<7;k++){
    float wl = Wl[k*H + col];
    float wr = Wr[k*H + col];
    #pragma unroll
    for (int t=0;t<8;t++){
      int node = n0+t; if (node >= n) node = n-1;
      float hv = x[(size_t)node*7 + k];
      accl[t] = fmaf(hv, wl, accl[t]);
      accr[t] = fmaf(hv, wr, accr[t]);
    }
  }
  #pragma unroll
  for (int t=0;t<8;t++){
    int node = n0+t;
    if (node < n){
      xl[(size_t)node*H + col] = __float2half(accl[t]);
      xr[(size_t)node*H + col] = __float2half(accr[t]);
    }
  }
}

// ------------- MFMA GEMM pair: h[n,128]f16 @ Wt -> xl,xr f16 (f32 accum) ------
// block 256 = 4 waves; wave: 16 rows x 256 cols; 16x16x32_f16, K=128 -> 4 steps
__global__ __launch_bounds__(256) void k_gemm2h(
    const __half* __restrict__ h, const _Float16* __restrict__ Wt,
    const float* __restrict__ bl, const float* __restrict__ br,
    __half* __restrict__ xl, __half* __restrict__ xr, int n){
  int wave = threadIdx.x >> 6, lane = threadIdx.x & 63;
  int m16 = lane & 15, quad = lane >> 4;
  int row0 = blockIdx.x*64 + wave*16;
  int arow = row0 + m16; if (arow >= n) arow = n-1;
  const __half* hr = h + (size_t)arow*H;
  half8 a[4];
  #pragma unroll
  for (int kb=0;kb<4;kb++) a[kb] = *(const half8*)(hr + kb*32 + quad*8);
  floatx4 acc[16];
  #pragma unroll
  for (int t=0;t<16;t++){ floatx4 z = {0.f,0.f,0.f,0.f}; acc[t] = z; }
  #pragma unroll
  for (int nt=0;nt<16;nt++){
    const _Float16* wr_ = Wt + (size_t)(nt*16 + m16)*H;
    #pragma unroll
    for (int kb=0;kb<4;kb++){
      half8 b = *(const half8*)(wr_ + kb*32 + quad*8);
      acc[nt] = __builtin_amdgcn_mfma_f32_16x16x32_f16(a[kb], b, acc[nt], 0,0,0);
    }
  }
  #pragma unroll
  for (int nt=0;nt<16;nt++){
    int c = nt*16 + m16;                 // D col = lane&15
    float bias; __half* dst; int cc;
    if (c < H){ bias = bl[c];   dst = xl; cc = c;   }
    else      { bias = br[c-H]; dst = xr; cc = c-H; }
    #pragma unroll
    for (int r=0;r<4;r++){
      int rw = row0 + quad*4 + r;        // D row = quad*4 + r
      if (rw < n) dst[(size_t)rw*H + cc] = __float2half(acc[nt][r] + bias);
    }
  }
}

// ------------- GATv2: 16 lanes/node, 8 feats/lane, DPP reduce, online softmax -
template<int POOL>
__global__ void k_gat(const __half* __restrict__ xl, const __half* __restrict__ xr,
                      const float* __restrict__ att, const float* __restrict__ bo,
                      const int* __restrict__ row_ptr, const int* __restrict__ csr_src,
                      __half* __restrict__ hout,
                      const int* __restrict__ batch, float* __restrict__ sums,
                      float* __restrict__ cnt, int n){
  int gid = (int)((blockIdx.x*blockDim.x + threadIdx.x) >> 4);
  int lane16 = threadIdx.x & 15;
  if (gid >= n) return;
  int f = lane16*8;
  float xrv[8], av[8];
  {
    float4 r = *(const float4*)(xr + (size_t)gid*H + f);
    const __half2* q = (const __half2*)&r;
    #pragma unroll
    for (int i=0;i<4;i++){ float2 t2 = __half22float2(q[i]); xrv[2*i]=t2.x; xrv[2*i+1]=t2.y; }
  }
  {
    float4 a0 = *(const float4*)(att + f);
    float4 a1 = *(const float4*)(att + f + 4);
    av[0]=a0.x; av[1]=a0.y; av[2]=a0.z; av[3]=a0.w;
    av[4]=a1.x; av[5]=a1.y; av[6]=a1.z; av[7]=a1.w;
  }
  float acc[8];
  #pragma unroll
  for (int i=0;i<8;i++) acc[i]=0.f;
  float mmax = -INFINITY, denom = 0.f;
  int beg = row_ptr[gid], end = row_ptr[gid+1];
  int j = beg;
  for (; j+1 < end; j += 2){
    int s0 = csr_src[j], s1 = csr_src[j+1];
    float4 r0 = *(const float4*)(xl + (size_t)s0*H + f);
    float4 r1 = *(const float4*)(xl + (size_t)s1*H + f);
    float v0[8], v1[8];
    {
      const __half2* q0 = (const __half2*)&r0;
      const __half2* q1 = (const __half2*)&r1;
      #pragma unroll
      for (int i=0;i<4;i++){
        float2 t0 = __half22float2(q0[i]); v0[2*i]=t0.x; v0[2*i+1]=t0.y;
        float2 t1 = __half22float2(q1[i]); v1[2*i]=t1.x; v1[2*i+1]=t1.y;
      }
    }
    float d0=0.f, d1=0.f;
    #pragma unroll
    for (int i=0;i<8;i++){
      float u0 = v0[i] + xrv[i];
      float u1 = v1[i] + xrv[i];
      float l0 = fmaf(0.4f, fabsf(u0), 0.6f*u0);   // leaky_relu(u,0.2)
      float l1 = fmaf(0.4f, fabsf(u1), 0.6f*u1);
      d0 = fmaf(l0, av[i], d0);
      d1 = fmaf(l1, av[i], d1);
    }
    d0 = grp16_sum(d0);
    d1 = grp16_sum(d1);
    float m2 = fmaxf(d0, d1);
    if (m2 > mmax){
      float sc = __expf(mmax - m2);
      #pragma unroll
      for (int i=0;i<8;i++) acc[i] *= sc;
      denom *= sc;
      mmax = m2;
    }
    float w0 = __expf(d0 - mmax), w1 = __expf(d1 - mmax);
    denom += w0 + w1;
    #pragma unroll
    for (int i=0;i<8;i++) acc[i] = fmaf(w0, v0[i], fmaf(w1, v1[i], acc[i]));
  }
  if (j < end){
    int s0 = csr_src[j];
    float4 r0 = *(const float4*)(xl + (size_t)s0*H + f);
    float v0[8];
    const __half2* q0 = (const __half2*)&r0;
    #pragma unroll
    for (int i=0;i<4;i++){ float2 t0 = __half22float2(q0[i]); v0[2*i]=t0.x; v0[2*i+1]=t0.y; }
    float d0=0.f;
    #pragma unroll
    for (int i=0;i<8;i++){
      float u0 = v0[i] + xrv[i];
      float l0 = fmaf(0.4f, fabsf(u0), 0.6f*u0);
      d0 = fmaf(l0, av[i], d0);
    }
    d0 = grp16_sum(d0);
    if (d0 > mmax){
      float sc = __expf(mmax - d0);
      #pragma unroll
      for (int i=0;i<8;i++) acc[i] *= sc;
      denom *= sc;
      mmax = d0;
    }
    float w0 = __expf(d0 - mmax);
    denom += w0;
    #pragma unroll
    for (int i=0;i<8;i++) acc[i] = fmaf(w0, v0[i], acc[i]);
  }
  float inv = 1.f/denom;
  float o[8];
  {
    float4 b0 = *(const float4*)(bo + f);
    float4 b1 = *(const float4*)(bo + f + 4);
    float bb[8] = {b0.x,b0.y,b0.z,b0.w,b1.x,b1.y,b1.z,b1.w};
    #pragma unroll
    for (int i=0;i<8;i++){
      float t = acc[i]*inv + bb[i];
      o[i] = t > 0.f ? t : expm1f(t);   // ELU
    }
  }
  if (POOL){
    int b = batch[gid];
    #pragma unroll
    for (int i=0;i<8;i++) atomicAdd(&sums[b*H + f + i], o[i]);
    if (lane16==0) atomicAdd(&cnt[b], 1.0f);
  } else {
    union { float4 f4; __half2 h2[4]; } u;
    #pragma unroll
    for (int i=0;i<4;i++) u.h2[i] = __floats2half2_rn(o[2*i], o[2*i+1]);
    *(float4*)(hout + (size_t)gid*H + f) = u.f4;
  }
}

// ---------------- fused MLP head + log_softmax ----------------
__global__ void k_fc(const float* __restrict__ sums, const float* __restrict__ cnt,
                     const float* __restrict__ W1, const float* __restrict__ b1,
                     const float* __restrict__ W2, const float* __restrict__ b2,
                     float* __restrict__ out){
  __shared__ float g[H];
  __shared__ float z[FCD];
  int gi = blockIdx.x;
  int t = threadIdx.x;     // 0..255
  float c = cnt[gi]; if (c < 1.f) c = 1.f;
  if (t < H) g[t] = sums[gi*H+t] / c;
  __syncthreads();
  float acc = b1[t];
  for (int k=0;k<H;k++) acc = fmaf(g[k], W1[k*FCD+t], acc);
  z[t] = acc > 0.f ? acc : 0.f;
  __syncthreads();
  if (t < 2){
    float l = b2[t];
    for (int k=0;k<FCD;k++) l = fmaf(z[k], W2[k*2+t], l);
    g[t] = l;
  }
  __syncthreads();
  if (t < 2){
    float l0 = g[0], l1 = g[1];
    float mx = fmaxf(l0,l1);
    float lse = mx + logf(__expf(l0-mx) + __expf(l1-mx));
    out[gi*2+t] = g[t] - lse;
  }
}

extern "C" void kernel_launch(void* const* d_in, const int* in_sizes, int n_in,
                              void* d_out, int out_size, void* d_ws, size_t ws_size,
                              hipStream_t stream) {
  const float* x     = (const float*)d_in[0];
  const int*   ei    = (const int*)  d_in[1];
  const int*   batch = (const int*)  d_in[2];
  const float* Wl[3]  = {(const float*)d_in[3],  (const float*)d_in[9],  (const float*)d_in[15]};
  const float* bl[3]  = {(const float*)d_in[4],  (const float*)d_in[10], (const float*)d_in[16]};
  const float* Wr[3]  = {(const float*)d_in[5],  (const float*)d_in[11], (const float*)d_in[17]};
  const float* br[3]  = {(const float*)d_in[6],  (const float*)d_in[12], (const float*)d_in[18]};
  const float* att[3] = {(const float*)d_in[7],  (const float*)d_in[13], (const float*)d_in[19]};
  const float* bo[3]  = {(const float*)d_in[8],  (const float*)d_in[14], (const float*)d_in[20]};
  const float* fc1W = (const float*)d_in[21];
  const float* fc1b = (const float*)d_in[22];
  const float* fc2W = (const float*)d_in[23];
  const float* fc2b = (const float*)d_in[24];

  const int N  = in_sizes[2];
  const int E  = in_sizes[1]/2;
  const int Et = E + N;
  const int G  = out_size/2;
  const int NB = (N + 255)/256;   // scan blocks (<=256)

  char* p = (char*)d_ws;
  auto alloc = [&](size_t bytes)->void*{
    void* r = (void*)p; p += (bytes + 255) & ~(size_t)255; return r;
  };
  int*      deg     = (int*)     alloc((size_t)N*4);
  int*      row_ptr = (int*)     alloc((size_t)(N+1)*4);
  int*      nxt     = (int*)     alloc((size_t)N*4);
  int*      bsum    = (int*)     alloc((size_t)256*4);
  int*      csr     = (int*)     alloc((size_t)Et*4);
  __half*   xl      = (__half*)  alloc((size_t)N*H*2);
  __half*   xr      = (__half*)  alloc((size_t)N*H*2);
  __half*   hbuf    = (__half*)  alloc((size_t)N*H*2);
  _Float16* Wt      = (_Float16*)alloc((size_t)2*256*H*2);
  float*    sums    = (float*)   alloc((size_t)G*H*4);
  float*    cnt     = (float*)   alloc((size_t)G*4);

  // CSR by dst (edge list static across layers)
  hipMemsetAsync(deg, 0, (size_t)N*4, stream);
  k_prep   <<<256, 256, 0, stream>>>(Wl[1], Wr[1], Wl[2], Wr[2], Wt);
  k_deg    <<<(Et+255)/256, 256, 0, stream>>>(ei, E, N, deg);
  k_scanA  <<<NB, 256, 0, stream>>>(deg, N, bsum);
  k_scanB  <<<1, 256, 0, stream>>>(bsum, NB, row_ptr + N);
  k_scanC  <<<NB, 256, 0, stream>>>(deg, bsum, N, row_ptr, nxt);
  k_scatter<<<(Et+255)/256, 256, 0, stream>>>(ei, E, N, nxt, csr);

  const int g7  = (N + 7)/8;
  const int gM  = (N + 63)/64;
  const int gg  = (int)(((size_t)N*16 + 255)/256);

  hipMemsetAsync(sums, 0, (size_t)G*H*4, stream);
  hipMemsetAsync(cnt,  0, (size_t)G*4,   stream);

  // layer 0 (K=7)
  k_gemm7<<<g7, 128, 0, stream>>>(x, Wl[0], bl[0], Wr[0], br[0], xl, xr, N);
  k_gat<0><<<gg, 256, 0, stream>>>(xl, xr, att[0], bo[0], row_ptr, csr, hbuf,
                                   batch, sums, cnt, N);
  // layer 1
  k_gemm2h<<<gM, 256, 0, stream>>>(hbuf, Wt, bl[1], br[1], xl, xr, N);
  k_gat<0><<<gg, 256, 0, stream>>>(xl, xr, att[1], bo[1], row_ptr, csr, hbuf,
                                   batch, sums, cnt, N);
  // layer 2 (+fused mean-pool accumulate)
  k_gemm2h<<<gM, 256, 0, stream>>>(hbuf, Wt + (size_t)256*H, bl[2], br[2], xl, xr, N);
  k_gat<1><<<gg, 256, 0, stream>>>(xl, xr, att[2], bo[2], row_ptr, csr, hbuf,
                                   batch, sums, cnt, N);

  // head
  k_fc<<<G, 256, 0, stream>>>(sums, cnt, fc1W, fc1b, fc2W, fc2b, (float*)d_out);
}

// Round 4
// 711.219 us; speedup vs baseline: 2.0534x; 1.2110x over previous
//
#include <hip/hip_runtime.h>
#include <hip/hip_fp16.h>
#include <math.h>

#define H 128
#define FCD 256

typedef _Float16 half8 __attribute__((ext_vector_type(8)));
typedef float floatx4 __attribute__((ext_vector_type(4)));

// ---------------- DPP 16-lane (row) reduction: 4 VALU adds, no LDS pipe -------
template<int CTRL>
__device__ __forceinline__ float dppadd(float x){
  return x + __int_as_float(__builtin_amdgcn_update_dpp(
      0, __float_as_int(x), CTRL, 0xf, 0xf, true));
}
__device__ __forceinline__ float grp16_sum(float x){
  x = dppadd<0x128>(x);   // row_ror:8
  x = dppadd<0x124>(x);   // row_ror:4
  x = dppadd<0x122>(x);   // row_ror:2
  x = dppadd<0x121>(x);   // row_ror:1
  return x;
}

// ---------------- CSR build ----------------
__global__ void k_deg(const int* __restrict__ ei, int E, int N, int* __restrict__ deg){
  int j = blockIdx.x*256 + threadIdx.x;
  if (j >= E+N) return;
  int dst = (j < E) ? ei[E+j] : (j-E);
  atomicAdd(&deg[dst], 1);
}

__global__ void k_scanA(const int* __restrict__ deg, int N, int* __restrict__ bsum){
  int t = threadIdx.x, lane = t & 63, w = t >> 6;
  int i = blockIdx.x*256 + t;
  int v = (i<N) ? deg[i] : 0;
  #pragma unroll
  for (int off=32; off; off>>=1) v += __shfl_xor(v, off);
  __shared__ int ws[4];
  if (lane==0) ws[w] = v;
  __syncthreads();
  if (t==0) bsum[blockIdx.x] = ws[0]+ws[1]+ws[2]+ws[3];
}

// exclusive scan of up to 256 ints, single block, in place
__global__ void k_scanB(int* __restrict__ bsum, int nb, int* __restrict__ totalp){
  int t = threadIdx.x, lane = t & 63, w = t >> 6;
  int v = (t<nb) ? bsum[t] : 0;
  int x = v;
  #pragma unroll
  for (int off=1; off<64; off<<=1){
    int y = __shfl_up(x, off);
    if (lane >= off) x += y;
  }
  __shared__ int ws[4];
  if (lane==63) ws[w] = x;
  __syncthreads();
  int woff = (w>0?ws[0]:0) + (w>1?ws[1]:0) + (w>2?ws[2]:0);
  int incl = x + woff;
  if (t<nb) bsum[t] = incl - v;         // exclusive
  if (t==255) *totalp = incl;
}

__global__ void k_scanC(const int* __restrict__ deg, const int* __restrict__ bsum, int N,
                        int* __restrict__ row_ptr, int* __restrict__ nxt){
  int t = threadIdx.x, lane = t & 63, w = t >> 6;
  int i = blockIdx.x*256 + t;
  int v = (i<N) ? deg[i] : 0;
  int x = v;
  #pragma unroll
  for (int off=1; off<64; off<<=1){
    int y = __shfl_up(x, off);
    if (lane >= off) x += y;
  }
  __shared__ int ws[4];
  if (lane==63) ws[w] = x;
  __syncthreads();
  int woff = (w>0?ws[0]:0) + (w>1?ws[1]:0) + (w>2?ws[2]:0);
  int excl = bsum[blockIdx.x] + woff + x - v;
  if (i<N){ row_ptr[i] = excl; nxt[i] = excl; }
}

__global__ void k_scatter(const int* __restrict__ ei, int E, int N,
                          int* __restrict__ nxt, int* __restrict__ csr_src){
  int j = blockIdx.x*256 + threadIdx.x;
  if (j >= E+N) return;
  int src, dst;
  if (j < E){ src = ei[j]; dst = ei[E+j]; } else { src = j-E; dst = j-E; }
  int pos = atomicAdd(&nxt[dst], 1);
  csr_src[pos] = src;
}

// ---------------- degree-bucket counting sort (equalize wave divergence) ------
__global__ void k_dhist(const int* __restrict__ deg, int N, int* __restrict__ dhist){
  __shared__ int lh[256];
  int t = threadIdx.x;
  lh[t] = 0;
  __syncthreads();
  int i = blockIdx.x*256 + t;
  if (i < N){ int d = min(deg[i], 255); atomicAdd(&lh[d], 1); }
  __syncthreads();
  if (lh[t]) atomicAdd(&dhist[t], lh[t]);
}

__global__ void k_dscatter(const int* __restrict__ deg, int N,
                           int* __restrict__ dnext, int* __restrict__ perm){
  int i = blockIdx.x*256 + threadIdx.x;
  if (i >= N) return;
  int d = min(deg[i], 255);
  int pos = atomicAdd(&dnext[d], 1);
  perm[pos] = i;
}

// ------------- weight prep: Wl/Wr (128x128 f32, k-major) -> Wt fp16 [L][n][k] --
__global__ void k_prep(const float* __restrict__ Wl1, const float* __restrict__ Wr1,
                       const float* __restrict__ Wl2, const float* __restrict__ Wr2,
                       _Float16* __restrict__ Wt){
  int idx = blockIdx.x*256 + threadIdx.x;   // 2*256*128 = 65536 total
  int L   = idx >> 15;
  int rem = idx & 32767;
  int nn  = rem >> 7;        // 0..255
  int k   = rem & 127;
  const float* W = (L==0) ? (nn<H?Wl1:Wr1) : (nn<H?Wl2:Wr2);
  Wt[idx] = (_Float16)W[k*H + (nn&127)];
}

// ---------------- layer-0 K=7 GEMM pair: x fp32 -> xl/xr fp16 ----------------
__global__ void k_gemm7(const float* __restrict__ x,
                        const float* __restrict__ Wl, const float* __restrict__ bl,
                        const float* __restrict__ Wr, const float* __restrict__ br,
                        __half* __restrict__ xl, __half* __restrict__ xr, int n){
  int col = threadIdx.x;            // 0..127
  int n0 = blockIdx.x*8;
  float accl[8], accr[8];
  float bL = bl[col], bR = br[col];
  #pragma unroll
  for (int t=0;t<8;t++){ accl[t]=bL; accr[t]=bR; }
  #pragma unroll
  for (int k=0;k<7;k++){
    float wl = Wl[k*H + col];
    float wr = Wr[k*H + col];
    #pragma unroll
    for (int t=0;t<8;t++){
      int node = n0+t; if (node >= n) node = n-1;
      float hv = x[(size_t)node*7 + k];
      accl[t] = fmaf(hv, wl, accl[t]);
      accr[t] = fmaf(hv, wr, accr[t]);
    }
  }
  #pragma unroll
  for (int t=0;t<8;t++){
    int node = n0+t;
    if (node < n){
      xl[(size_t)node*H + col] = __float2half(accl[t]);
      xr[(size_t)node*H + col] = __float2half(accr[t]);
    }
  }
}

// ------------- MFMA GEMM pair: h[n,128]f16 @ Wt -> xl,xr f16 (f32 accum) ------
__global__ __launch_bounds__(256) void k_gemm2h(
    const __half* __restrict__ h, const _Float16* __restrict__ Wt,
    const float* __restrict__ bl, const float* __restrict__ br,
    __half* __restrict__ xl, __half* __restrict__ xr, int n){
  int wave = threadIdx.x >> 6, lane = threadIdx.x & 63;
  int m16 = lane & 15, quad = lane >> 4;
  int row0 = blockIdx.x*64 + wave*16;
  int arow = row0 + m16; if (arow >= n) arow = n-1;
  const __half* hr = h + (size_t)arow*H;
  half8 a[4];
  #pragma unroll
  for (int kb=0;kb<4;kb++) a[kb] = *(const half8*)(hr + kb*32 + quad*8);
  floatx4 acc[16];
  #pragma unroll
  for (int t=0;t<16;t++){ floatx4 z = {0.f,0.f,0.f,0.f}; acc[t] = z; }
  #pragma unroll
  for (int nt=0;nt<16;nt++){
    const _Float16* wr_ = Wt + (size_t)(nt*16 + m16)*H;
    #pragma unroll
    for (int kb=0;kb<4;kb++){
      half8 b = *(const half8*)(wr_ + kb*32 + quad*8);
      acc[nt] = __builtin_amdgcn_mfma_f32_16x16x32_f16(a[kb], b, acc[nt], 0,0,0);
    }
  }
  #pragma unroll
  for (int nt=0;nt<16;nt++){
    int c = nt*16 + m16;                 // D col = lane&15
    float bias; __half* dst; int cc;
    if (c < H){ bias = bl[c];   dst = xl; cc = c;   }
    else      { bias = br[c-H]; dst = xr; cc = c-H; }
    #pragma unroll
    for (int r=0;r<4;r++){
      int rw = row0 + quad*4 + r;        // D row = quad*4 + r
      if (rw < n) dst[(size_t)rw*H + cc] = __float2half(acc[nt][r] + bias);
    }
  }
}

// ------------- GATv2: 16 lanes/node, 8 feats/lane, DPP reduce, online softmax -
__global__ void k_gat(const __half* __restrict__ xl, const __half* __restrict__ xr,
                      const float* __restrict__ att, const float* __restrict__ bo,
                      const int* __restrict__ row_ptr, const int* __restrict__ csr_src,
                      const int* __restrict__ perm,
                      __half* __restrict__ hout, int n){
  int gid0 = (int)((blockIdx.x*blockDim.x + threadIdx.x) >> 4);
  int lane16 = threadIdx.x & 15;
  if (gid0 >= n) return;
  int gid = perm[gid0];                  // degree-sorted order
  int f = lane16*8;
  float xrv[8], av[8];
  {
    float4 r = *(const float4*)(xr + (size_t)gid*H + f);
    const __half2* q = (const __half2*)&r;
    #pragma unroll
    for (int i=0;i<4;i++){ float2 t2 = __half22float2(q[i]); xrv[2*i]=t2.x; xrv[2*i+1]=t2.y; }
  }
  {
    float4 a0 = *(const float4*)(att + f);
    float4 a1 = *(const float4*)(att + f + 4);
    av[0]=a0.x; av[1]=a0.y; av[2]=a0.z; av[3]=a0.w;
    av[4]=a1.x; av[5]=a1.y; av[6]=a1.z; av[7]=a1.w;
  }
  float acc[8];
  #pragma unroll
  for (int i=0;i<8;i++) acc[i]=0.f;
  float mmax = -INFINITY, denom = 0.f;
  int beg = row_ptr[gid], end = row_ptr[gid+1];
  int j = beg;
  for (; j+3 < end; j += 4){
    int s[4];
    #pragma unroll
    for (int u=0;u<4;u++) s[u] = csr_src[j+u];
    float4 r[4];
    #pragma unroll
    for (int u=0;u<4;u++) r[u] = *(const float4*)(xl + (size_t)s[u]*H + f);
    float v[4][8], d[4];
    #pragma unroll
    for (int u=0;u<4;u++){
      const __half2* q = (const __half2*)&r[u];
      #pragma unroll
      for (int i=0;i<4;i++){
        float2 t2 = __half22float2(q[i]); v[u][2*i]=t2.x; v[u][2*i+1]=t2.y;
      }
      float du = 0.f;
      #pragma unroll
      for (int i=0;i<8;i++){
        float uu = v[u][i] + xrv[i];
        float lu = fmaf(0.4f, fabsf(uu), 0.6f*uu);   // leaky_relu(u,0.2)
        du = fmaf(lu, av[i], du);
      }
      d[u] = du;
    }
    #pragma unroll
    for (int u=0;u<4;u++) d[u] = grp16_sum(d[u]);
    float m4 = fmaxf(fmaxf(d[0],d[1]), fmaxf(d[2],d[3]));
    if (m4 > mmax){
      float sc = __expf(mmax - m4);
      #pragma unroll
      for (int i=0;i<8;i++) acc[i] *= sc;
      denom *= sc;
      mmax = m4;
    }
    float w[4];
    #pragma unroll
    for (int u=0;u<4;u++){ w[u] = __expf(d[u] - mmax); denom += w[u]; }
    #pragma unroll
    for (int i=0;i<8;i++)
      acc[i] = fmaf(w[0], v[0][i], fmaf(w[1], v[1][i],
               fmaf(w[2], v[2][i], fmaf(w[3], v[3][i], acc[i]))));
  }
  for (; j<end; j++){
    int s0 = csr_src[j];
    float4 r0 = *(const float4*)(xl + (size_t)s0*H + f);
    float v0[8];
    const __half2* q0 = (const __half2*)&r0;
    #pragma unroll
    for (int i=0;i<4;i++){ float2 t0 = __half22float2(q0[i]); v0[2*i]=t0.x; v0[2*i+1]=t0.y; }
    float d0=0.f;
    #pragma unroll
    for (int i=0;i<8;i++){
      float u0 = v0[i] + xrv[i];
      float l0 = fmaf(0.4f, fabsf(u0), 0.6f*u0);
      d0 = fmaf(l0, av[i], d0);
    }
    d0 = grp16_sum(d0);
    if (d0 > mmax){
      float sc = __expf(mmax - d0);
      #pragma unroll
      for (int i=0;i<8;i++) acc[i] *= sc;
      denom *= sc;
      mmax = d0;
    }
    float w0 = __expf(d0 - mmax);
    denom += w0;
    #pragma unroll
    for (int i=0;i<8;i++) acc[i] = fmaf(w0, v0[i], acc[i]);
  }
  float inv = 1.f/denom;
  float o[8];
  {
    float4 b0 = *(const float4*)(bo + f);
    float4 b1 = *(const float4*)(bo + f + 4);
    float bb[8] = {b0.x,b0.y,b0.z,b0.w,b1.x,b1.y,b1.z,b1.w};
    #pragma unroll
    for (int i=0;i<8;i++){
      float t = acc[i]*inv + bb[i];
      o[i] = t > 0.f ? t : expm1f(t);   // ELU
    }
  }
  union { float4 f4; __half2 h2[4]; } u;
  #pragma unroll
  for (int i=0;i<4;i++) u.h2[i] = __floats2half2_rn(o[2*i], o[2*i+1]);
  *(float4*)(hout + (size_t)gid*H + f) = u.f4;
}

// --------- fused segment mean-pool (sorted batch, binary search) + MLP head ---
__global__ void k_fc(const __half* __restrict__ hbuf, const int* __restrict__ batch, int N,
                     const float* __restrict__ W1, const float* __restrict__ b1,
                     const float* __restrict__ W2, const float* __restrict__ b2,
                     float* __restrict__ out){
  __shared__ float g[H];
  __shared__ float2 part[4][64];
  __shared__ float zs[FCD];
  __shared__ int bounds[2];
  int gi = blockIdx.x;
  int t = threadIdx.x;     // 0..255
  if (t < 2){
    int target = gi + t;
    int lo = 0, hi = N;
    while (lo < hi){ int mid = (lo+hi)>>1; if (batch[mid] < target) lo = mid+1; else hi = mid; }
    bounds[t] = lo;
  }
  __syncthreads();
  int lo = bounds[0], hi = bounds[1];
  int pairc = t & 63, slice = t >> 6;
  float sx = 0.f, sy = 0.f;
  for (int node = lo + slice; node < hi; node += 4){
    float2 f2 = __half22float2(*(const __half2*)(hbuf + (size_t)node*H + pairc*2));
    sx += f2.x; sy += f2.y;
  }
  part[slice][pairc] = make_float2(sx, sy);
  __syncthreads();
  if (t < 64){
    float2 a = part[0][t], b = part[1][t], c = part[2][t], d = part[3][t];
    float cnt = (float)(hi - lo); if (cnt < 1.f) cnt = 1.f;
    float inv = 1.f/cnt;
    g[2*t]   = (a.x+b.x+c.x+d.x)*inv;
    g[2*t+1] = (a.y+b.y+c.y+d.y)*inv;
  }
  __syncthreads();
  float acc = b1[t];
  for (int k=0;k<H;k++) acc = fmaf(g[k], W1[k*FCD+t], acc);
  zs[t] = acc > 0.f ? acc : 0.f;
  __syncthreads();
  if (t < 2){
    float l = b2[t];
    for (int k=0;k<FCD;k++) l = fmaf(zs[k], W2[k*2+t], l);
    g[t] = l;
  }
  __syncthreads();
  if (t < 2){
    float l0 = g[0], l1 = g[1];
    float mx = fmaxf(l0,l1);
    float lse = mx + logf(__expf(l0-mx) + __expf(l1-mx));
    out[gi*2+t] = g[t] - lse;
  }
}

extern "C" void kernel_launch(void* const* d_in, const int* in_sizes, int n_in,
                              void* d_out, int out_size, void* d_ws, size_t ws_size,
                              hipStream_t stream) {
  const float* x     = (const float*)d_in[0];
  const int*   ei    = (const int*)  d_in[1];
  const int*   batch = (const int*)  d_in[2];
  const float* Wl[3]  = {(const float*)d_in[3],  (const float*)d_in[9],  (const float*)d_in[15]};
  const float* bl[3]  = {(const float*)d_in[4],  (const float*)d_in[10], (const float*)d_in[16]};
  const float* Wr[3]  = {(const float*)d_in[5],  (const float*)d_in[11], (const float*)d_in[17]};
  const float* br[3]  = {(const float*)d_in[6],  (const float*)d_in[12], (const float*)d_in[18]};
  const float* att[3] = {(const float*)d_in[7],  (const float*)d_in[13], (const float*)d_in[19]};
  const float* bo[3]  = {(const float*)d_in[8],  (const float*)d_in[14], (const float*)d_in[20]};
  const float* fc1W = (const float*)d_in[21];
  const float* fc1b = (const float*)d_in[22];
  const float* fc2W = (const float*)d_in[23];
  const float* fc2b = (const float*)d_in[24];

  const int N  = in_sizes[2];
  const int E  = in_sizes[1]/2;
  const int Et = E + N;
  const int G  = out_size/2;
  const int NB = (N + 255)/256;   // scan blocks (<=256)

  char* p = (char*)d_ws;
  auto alloc = [&](size_t bytes)->void*{
    void* r = (void*)p; p += (bytes + 255) & ~(size_t)255; return r;
  };
  int*      deg     = (int*)     alloc((size_t)N*4);
  int*      row_ptr = (int*)     alloc((size_t)(N+1)*4);
  int*      nxt     = (int*)     alloc((size_t)N*4);
  int*      bsum    = (int*)     alloc((size_t)256*4);
  int*      dhist   = (int*)     alloc((size_t)256*4);
  int*      scratch = (int*)     alloc((size_t)256*4);
  int*      perm    = (int*)     alloc((size_t)N*4);
  int*      csr     = (int*)     alloc((size_t)Et*4);
  __half*   xl      = (__half*)  alloc((size_t)N*H*2);
  __half*   xr      = (__half*)  alloc((size_t)N*H*2);
  __half*   hbuf    = (__half*)  alloc((size_t)N*H*2);
  _Float16* Wt      = (_Float16*)alloc((size_t)2*256*H*2);

  // CSR by dst (edge list static across layers)
  hipMemsetAsync(deg,   0, (size_t)N*4,   stream);
  hipMemsetAsync(dhist, 0, (size_t)256*4, stream);
  k_prep   <<<256, 256, 0, stream>>>(Wl[1], Wr[1], Wl[2], Wr[2], Wt);
  k_deg    <<<(Et+255)/256, 256, 0, stream>>>(ei, E, N, deg);
  k_scanA  <<<NB, 256, 0, stream>>>(deg, N, bsum);
  k_scanB  <<<1, 256, 0, stream>>>(bsum, NB, row_ptr + N);
  k_scanC  <<<NB, 256, 0, stream>>>(deg, bsum, N, row_ptr, nxt);
  k_scatter<<<(Et+255)/256, 256, 0, stream>>>(ei, E, N, nxt, csr);
  // degree-bucket counting sort -> perm
  k_dhist   <<<NB, 256, 0, stream>>>(deg, N, dhist);
  k_scanB   <<<1, 256, 0, stream>>>(dhist, 256, scratch);
  k_dscatter<<<NB, 256, 0, stream>>>(deg, N, dhist, perm);

  const int g7  = (N + 7)/8;
  const int gM  = (N + 63)/64;
  const int gg  = (int)(((size_t)N*16 + 255)/256);

  // layer 0 (K=7)
  k_gemm7<<<g7, 128, 0, stream>>>(x, Wl[0], bl[0], Wr[0], br[0], xl, xr, N);
  k_gat<<<gg, 256, 0, stream>>>(xl, xr, att[0], bo[0], row_ptr, csr, perm, hbuf, N);
  // layer 1
  k_gemm2h<<<gM, 256, 0, stream>>>(hbuf, Wt, bl[1], br[1], xl, xr, N);
  k_gat<<<gg, 256, 0, stream>>>(xl, xr, att[1], bo[1], row_ptr, csr, perm, hbuf, N);
  // layer 2
  k_gemm2h<<<gM, 256, 0, stream>>>(hbuf, Wt + (size_t)256*H, bl[2], br[2], xl, xr, N);
  k_gat<<<gg, 256, 0, stream>>>(xl, xr, att[2], bo[2], row_ptr, csr, perm, hbuf, N);

  // fused pool + head (sorted batch, no atomics)
  k_fc<<<G, 256, 0, stream>>>(hbuf, batch, N, fc1W, fc1b, fc2W, fc2b, (float*)d_out);
}

// Round 8
// 575.457 us; speedup vs baseline: 2.5378x; 1.2359x over previous
//
#include <hip/hip_runtime.h>
#include <hip/hip_fp16.h>
#include <math.h>

#define H 128
#define FCD 256
#define BUKSH 7                    // 128 dst nodes per bucket
#define MAXBUK 512                 // supports N <= 65536

typedef _Float16 half8 __attribute__((ext_vector_type(8)));
typedef float floatx4 __attribute__((ext_vector_type(4)));

// ---------------- DPP 16-lane (row) reduction: 4 VALU adds, no LDS pipe -------
template<int CTRL>
__device__ __forceinline__ float dppadd(float x){
  return x + __int_as_float(__builtin_amdgcn_update_dpp(
      0, __float_as_int(x), CTRL, 0xf, 0xf, true));
}
__device__ __forceinline__ float grp16_sum(float x){
  x = dppadd<0x128>(x);   // row_ror:8
  x = dppadd<0x124>(x);   // row_ror:4
  x = dppadd<0x122>(x);   // row_ror:2
  x = dppadd<0x121>(x);   // row_ror:1
  return x;
}

// ---------------- generic single-block exclusive scan (nb <= 512) -------------
__global__ void k_scan512(const int* __restrict__ in, int nb,
                          int* __restrict__ out1, int* __restrict__ out2){
  int t = threadIdx.x, lane = t & 63, w = t >> 6;
  int v = (t<nb) ? in[t] : 0;
  int x = v;
  #pragma unroll
  for (int off=1; off<64; off<<=1){
    int y = __shfl_up(x, off);
    if (lane >= off) x += y;
  }
  __shared__ int ws[8];
  if (lane==63) ws[w] = x;
  __syncthreads();
  int wo = 0;
  #pragma unroll
  for (int i=0;i<8;i++) if (i<w) wo += ws[i];
  int excl = wo + x - v;
  if (t<nb){ out1[t] = excl; if (out2) out2[t] = excl; }
  if (t==511) out1[nb] = wo + x;
}

// ---------------- bucketed CSR build ----------------
__global__ void k_bhist(const int* __restrict__ ei, int E, int Et, int nbuk,
                        int* __restrict__ bhist){
  __shared__ int lh[MAXBUK];
  int t = threadIdx.x;
  lh[t] = 0;
  __syncthreads();
  int j0 = blockIdx.x*4096;
  #pragma unroll
  for (int i=0;i<8;i++){
    int j = j0 + i*512 + t;
    if (j < Et){
      int dst = (j < E) ? ei[E+j] : (j - E);
      atomicAdd(&lh[dst>>BUKSH], 1);
    }
  }
  __syncthreads();
  if (t < nbuk && lh[t]) atomicAdd(&bhist[t], lh[t]);
}

__global__ void k_bscatter(const int* __restrict__ ei, int E, int Et, int nbuk,
                           int* __restrict__ bnext, unsigned* __restrict__ ebuf){
  __shared__ int lh[MAXBUK];
  __shared__ int lbase[MAXBUK];
  int t = threadIdx.x;
  lh[t] = 0;
  __syncthreads();
  int j0 = blockIdx.x*4096;
  unsigned pk[8]; int bk[8]; int rk[8];
  #pragma unroll
  for (int i=0;i<8;i++){
    int j = j0 + i*512 + t;
    if (j < Et){
      int src, dst;
      if (j < E){ src = ei[j]; dst = ei[E+j]; } else { src = dst = j - E; }
      pk[i] = (unsigned)src | ((unsigned)dst << 16);
      bk[i] = dst >> BUKSH;
      rk[i] = atomicAdd(&lh[bk[i]], 1);
    }
  }
  __syncthreads();
  if (t < nbuk){
    int c = lh[t];
    lbase[t] = c ? atomicAdd(&bnext[t], c) : 0;
  }
  __syncthreads();
  #pragma unroll
  for (int i=0;i<8;i++){
    int j = j0 + i*512 + t;
    if (j < Et) ebuf[lbase[bk[i]] + rk[i]] = pk[i];
  }
}

__global__ void k_bdeg(const unsigned* __restrict__ ebuf, const int* __restrict__ bbase,
                       int N, int* __restrict__ deg){
  __shared__ int cnt[1<<BUKSH];
  int b = blockIdx.x, t = threadIdx.x;
  if (t < (1<<BUKSH)) cnt[t] = 0;
  __syncthreads();
  int lo = bbase[b], hi = bbase[b+1];
  for (int j = lo + t; j < hi; j += 256){
    unsigned d = ebuf[j] >> 16;
    atomicAdd(&cnt[d & ((1<<BUKSH)-1)], 1);
  }
  __syncthreads();
  if (t < (1<<BUKSH)){
    int node = (b<<BUKSH) + t;
    if (node < N) deg[node] = cnt[t];
  }
}

__global__ void k_bcsr(const unsigned* __restrict__ ebuf, const int* __restrict__ bbase,
                       const int* __restrict__ row_ptr, int* __restrict__ csr){
  __shared__ int lnxt[1<<BUKSH];
  int b = blockIdx.x, t = threadIdx.x;
  if (t < (1<<BUKSH)) lnxt[t] = 0;
  __syncthreads();
  int lo = bbase[b], hi = bbase[b+1];
  for (int j = lo + t; j < hi; j += 256){
    unsigned e = ebuf[j];
    int dst = e >> 16, src = e & 0xffff;
    int r = atomicAdd(&lnxt[dst & ((1<<BUKSH)-1)], 1);
    csr[row_ptr[dst] + r] = src;
  }
}

// ---------------- row_ptr scan over deg ----------------
__global__ void k_scanA(const int* __restrict__ deg, int N, int* __restrict__ bsum){
  int t = threadIdx.x, lane = t & 63, w = t >> 6;
  int i = blockIdx.x*256 + t;
  int v = (i<N) ? deg[i] : 0;
  #pragma unroll
  for (int off=32; off; off>>=1) v += __shfl_xor(v, off);
  __shared__ int ws[4];
  if (lane==0) ws[w] = v;
  __syncthreads();
  if (t==0) bsum[blockIdx.x] = ws[0]+ws[1]+ws[2]+ws[3];
}

// FIX (R7->R8): row_ptr[N] was never written (0xAA poison) -> node N-1 got
// end<beg -> denom=0 -> inf outputs. Thread (0,0) now writes row_ptr[N]=total.
__global__ void k_scanC(const int* __restrict__ deg, const int* __restrict__ bsum, int N,
                        int total, int* __restrict__ row_ptr){
  int t = threadIdx.x, lane = t & 63, w = t >> 6;
  if (blockIdx.x==0 && t==0) row_ptr[N] = total;
  int i = blockIdx.x*256 + t;
  int v = (i<N) ? deg[i] : 0;
  int x = v;
  #pragma unroll
  for (int off=1; off<64; off<<=1){
    int y = __shfl_up(x, off);
    if (lane >= off) x += y;
  }
  __shared__ int ws[4];
  if (lane==63) ws[w] = x;
  __syncthreads();
  int woff = (w>0?ws[0]:0) + (w>1?ws[1]:0) + (w>2?ws[2]:0);
  int excl = bsum[blockIdx.x] + woff + x - v;
  if (i<N) row_ptr[i] = excl;
}

// ---------------- degree-bucket counting sort (equalize wave divergence) ------
__global__ void k_dhist(const int* __restrict__ deg, int N, int* __restrict__ dhist){
  __shared__ int lh[256];
  int t = threadIdx.x;
  lh[t] = 0;
  __syncthreads();
  int i = blockIdx.x*256 + t;
  if (i < N){ int d = min(deg[i], 255); atomicAdd(&lh[d], 1); }
  __syncthreads();
  if (lh[t]) atomicAdd(&dhist[t], lh[t]);
}

__global__ void k_dscatter(const int* __restrict__ deg, int N,
                           int* __restrict__ dnext, int* __restrict__ perm){
  int i = blockIdx.x*256 + threadIdx.x;
  if (i >= N) return;
  int d = min(deg[i], 255);
  int pos = atomicAdd(&dnext[d], 1);
  perm[pos] = i;
}

// ------------- weight prep: Wl/Wr (128x128 f32, k-major) -> Wt fp16 [L][n][k] --
__global__ void k_prep(const float* __restrict__ Wl1, const float* __restrict__ Wr1,
                       const float* __restrict__ Wl2, const float* __restrict__ Wr2,
                       _Float16* __restrict__ Wt){
  int idx = blockIdx.x*256 + threadIdx.x;   // 2*256*128 = 65536 total
  int L   = idx >> 15;
  int rem = idx & 32767;
  int nn  = rem >> 7;        // 0..255
  int k   = rem & 127;
  const float* W = (L==0) ? (nn<H?Wl1:Wr1) : (nn<H?Wl2:Wr2);
  Wt[idx] = (_Float16)W[k*H + (nn&127)];
}

// ---------------- layer-0 K=7 GEMM pair: x fp32 -> xl/xr fp16 ----------------
__global__ void k_gemm7(const float* __restrict__ x,
                        const float* __restrict__ Wl, const float* __restrict__ bl,
                        const float* __restrict__ Wr, const float* __restrict__ br,
                        __half* __restrict__ xl, __half* __restrict__ xr, int n){
  int col = threadIdx.x;            // 0..127
  int n0 = blockIdx.x*8;
  float accl[8], accr[8];
  float bL = bl[col], bR = br[col];
  #pragma unroll
  for (int t=0;t<8;t++){ accl[t]=bL; accr[t]=bR; }
  #pragma unroll
  for (int k=0;k<7;k++){
    float wl = Wl[k*H + col];
    float wr = Wr[k*H + col];
    #pragma unroll
    for (int t=0;t<8;t++){
      int node = n0+t; if (node >= n) node = n-1;
      float hv = x[(size_t)node*7 + k];
      accl[t] = fmaf(hv, wl, accl[t]);
      accr[t] = fmaf(hv, wr, accr[t]);
    }
  }
  #pragma unroll
  for (int t=0;t<8;t++){
    int node = n0+t;
    if (node < n){
      xl[(size_t)node*H + col] = __float2half(accl[t]);
      xr[(size_t)node*H + col] = __float2half(accr[t]);
    }
  }
}

// ------------- MFMA GEMM pair: h[n,128]f16 @ Wt -> xl,xr f16 (f32 accum) ------
__global__ __launch_bounds__(256) void k_gemm2h(
    const __half* __restrict__ h, const _Float16* __restrict__ Wt,
    const float* __restrict__ bl, const float* __restrict__ br,
    __half* __restrict__ xl, __half* __restrict__ xr, int n){
  int wave = threadIdx.x >> 6, lane = threadIdx.x & 63;
  int m16 = lane & 15, quad = lane >> 4;
  int row0 = blockIdx.x*64 + wave*16;
  int arow = row0 + m16; if (arow >= n) arow = n-1;
  const __half* hr = h + (size_t)arow*H;
  half8 a[4];
  #pragma unroll
  for (int kb=0;kb<4;kb++) a[kb] = *(const half8*)(hr + kb*32 + quad*8);
  floatx4 acc[16];
  #pragma unroll
  for (int t=0;t<16;t++){ floatx4 z = {0.f,0.f,0.f,0.f}; acc[t] = z; }
  #pragma unroll
  for (int nt=0;nt<16;nt++){
    const _Float16* wr_ = Wt + (size_t)(nt*16 + m16)*H;
    #pragma unroll
    for (int kb=0;kb<4;kb++){
      half8 b = *(const half8*)(wr_ + kb*32 + quad*8);
      acc[nt] = __builtin_amdgcn_mfma_f32_16x16x32_f16(a[kb], b, acc[nt], 0,0,0);
    }
  }
  #pragma unroll
  for (int nt=0;nt<16;nt++){
    int c = nt*16 + m16;                 // D col = lane&15
    float bias; __half* dst; int cc;
    if (c < H){ bias = bl[c];   dst = xl; cc = c;   }
    else      { bias = br[c-H]; dst = xr; cc = c-H; }
    #pragma unroll
    for (int r=0;r<4;r++){
      int rw = row0 + quad*4 + r;        // D row = quad*4 + r
      if (rw < n) dst[(size_t)rw*H + cc] = __float2half(acc[nt][r] + bias);
    }
  }
}

// ------------- GATv2: 16 lanes/node, 8 feats/lane, unroll-8, fp32 edge math ---
__global__ void k_gat(const __half* __restrict__ xl, const __half* __restrict__ xr,
                      const float* __restrict__ att, const float* __restrict__ bo,
                      const int* __restrict__ row_ptr, const int* __restrict__ csr_src,
                      const int* __restrict__ perm,
                      __half* __restrict__ hout, int n){
  int gid0 = (int)((blockIdx.x*blockDim.x + threadIdx.x) >> 4);
  int lane16 = threadIdx.x & 15;
  if (gid0 >= n) return;
  int gid = perm[gid0];                  // degree-sorted order
  int f = lane16*8;
  float xrv[8], av[8];
  {
    union { float4 q; __half2 h[4]; } U;
    U.q = *(const float4*)(xr + (size_t)gid*H + f);
    #pragma unroll
    for (int i=0;i<4;i++){ float2 t2 = __half22float2(U.h[i]); xrv[2*i]=t2.x; xrv[2*i+1]=t2.y; }
    float4 a0 = *(const float4*)(att + f);
    float4 a1 = *(const float4*)(att + f + 4);
    av[0]=a0.x; av[1]=a0.y; av[2]=a0.z; av[3]=a0.w;
    av[4]=a1.x; av[5]=a1.y; av[6]=a1.z; av[7]=a1.w;
  }
  float acc[8];
  #pragma unroll
  for (int i=0;i<8;i++) acc[i]=0.f;
  float mmax = -INFINITY, denom = 0.f;
  int beg = row_ptr[gid], end = row_ptr[gid+1];
  int j = beg;
  for (; j+7 < end; j += 8){
    int s[8];
    #pragma unroll
    for (int u=0;u<8;u++) s[u] = csr_src[j+u];
    float4 r[8];
    #pragma unroll
    for (int u=0;u<8;u++) r[u] = *(const float4*)(xl + (size_t)s[u]*H + f);
    float d[8];
    #pragma unroll
    for (int u=0;u<8;u++){
      union { float4 q; __half2 h[4]; } U; U.q = r[u];
      float dd = 0.f;
      #pragma unroll
      for (int i=0;i<4;i++){
        float2 vf = __half22float2(U.h[i]);
        float u0 = vf.x + xrv[2*i];
        float u1 = vf.y + xrv[2*i+1];
        float l0 = fmaf(0.4f, fabsf(u0), 0.6f*u0);   // leaky_relu(u,0.2)
        float l1 = fmaf(0.4f, fabsf(u1), 0.6f*u1);
        dd = fmaf(l0, av[2*i], fmaf(l1, av[2*i+1], dd));
      }
      d[u] = dd;
    }
    #pragma unroll
    for (int u=0;u<8;u++) d[u] = grp16_sum(d[u]);
    float m8 = fmaxf(fmaxf(fmaxf(d[0],d[1]), fmaxf(d[2],d[3])),
                     fmaxf(fmaxf(d[4],d[5]), fmaxf(d[6],d[7])));
    if (m8 > mmax){
      float sc = __expf(mmax - m8);
      #pragma unroll
      for (int i=0;i<8;i++) acc[i] *= sc;
      denom *= sc;
      mmax = m8;
    }
    #pragma unroll
    for (int u=0;u<8;u++){
      float w = __expf(d[u] - mmax);
      denom += w;
      union { float4 q; __half2 h[4]; } U; U.q = r[u];
      #pragma unroll
      for (int i=0;i<4;i++){
        float2 vf = __half22float2(U.h[i]);
        acc[2*i]   = fmaf(w, vf.x, acc[2*i]);
        acc[2*i+1] = fmaf(w, vf.y, acc[2*i+1]);
      }
    }
  }
  for (; j<end; j++){
    int s0 = csr_src[j];
    union { float4 q; __half2 h[4]; } U;
    U.q = *(const float4*)(xl + (size_t)s0*H + f);
    float v0[8];
    #pragma unroll
    for (int i=0;i<4;i++){ float2 t0 = __half22float2(U.h[i]); v0[2*i]=t0.x; v0[2*i+1]=t0.y; }
    float dd = 0.f;
    #pragma unroll
    for (int i=0;i<8;i++){
      float u0 = v0[i] + xrv[i];
      float l0 = fmaf(0.4f, fabsf(u0), 0.6f*u0);
      dd = fmaf(l0, av[i], dd);
    }
    dd = grp16_sum(dd);
    if (dd > mmax){
      float sc = __expf(mmax - dd);
      #pragma unroll
      for (int i=0;i<8;i++) acc[i] *= sc;
      denom *= sc;
      mmax = dd;
    }
    float w = __expf(dd - mmax);
    denom += w;
    #pragma unroll
    for (int i=0;i<8;i++) acc[i] = fmaf(w, v0[i], acc[i]);
  }
  float inv = 1.f/denom;
  float o[8];
  {
    float4 b0 = *(const float4*)(bo + f);
    float4 b1 = *(const float4*)(bo + f + 4);
    float bb[8] = {b0.x,b0.y,b0.z,b0.w,b1.x,b1.y,b1.z,b1.w};
    #pragma unroll
    for (int i=0;i<8;i++){
      float t = acc[i]*inv + bb[i];
      o[i] = t > 0.f ? t : expm1f(t);   // ELU
    }
  }
  union { float4 f4; __half2 h2[4]; } u;
  #pragma unroll
  for (int i=0;i<4;i++) u.h2[i] = __floats2half2_rn(o[2*i], o[2*i+1]);
  *(float4*)(hout + (size_t)gid*H + f) = u.f4;
}

// --------- fused segment mean-pool (sorted batch, binary search) + MLP head ---
__global__ void k_fc(const __half* __restrict__ hbuf, const int* __restrict__ batch, int N,
                     const float* __restrict__ W1, const float* __restrict__ b1,
                     const float* __restrict__ W2, const float* __restrict__ b2,
                     float* __restrict__ out){
  __shared__ float g[H];
  __shared__ float2 part[4][64];
  __shared__ float zs[FCD];
  __shared__ int bounds[2];
  int gi = blockIdx.x;
  int t = threadIdx.x;     // 0..255
  if (t < 2){
    int target = gi + t;
    int lo = 0, hi = N;
    while (lo < hi){ int mid = (lo+hi)>>1; if (batch[mid] < target) lo = mid+1; else hi = mid; }
    bounds[t] = lo;
  }
  __syncthreads();
  int lo = bounds[0], hi = bounds[1];
  int pairc = t & 63, slice = t >> 6;
  float sx = 0.f, sy = 0.f;
  for (int node = lo + slice; node < hi; node += 4){
    float2 f2 = __half22float2(*(const __half2*)(hbuf + (size_t)node*H + pairc*2));
    sx += f2.x; sy += f2.y;
  }
  part[slice][pairc] = make_float2(sx, sy);
  __syncthreads();
  if (t < 64){
    float2 a = part[0][t], b = part[1][t], c = part[2][t], d = part[3][t];
    float cnt = (float)(hi - lo); if (cnt < 1.f) cnt = 1.f;
    float inv = 1.f/cnt;
    g[2*t]   = (a.x+b.x+c.x+d.x)*inv;
    g[2*t+1] = (a.y+b.y+c.y+d.y)*inv;
  }
  __syncthreads();
  float acc = b1[t];
  for (int k=0;k<H;k++) acc = fmaf(g[k], W1[k*FCD+t], acc);
  zs[t] = acc > 0.f ? acc : 0.f;
  __syncthreads();
  if (t < 2){
    float l = b2[t];
    for (int k=0;k<FCD;k++) l = fmaf(zs[k], W2[k*2+t], l);
    g[t] = l;
  }
  __syncthreads();
  if (t < 2){
    float l0 = g[0], l1 = g[1];
    float mx = fmaxf(l0,l1);
    float lse = mx + logf(__expf(l0-mx) + __expf(l1-mx));
    out[gi*2+t] = g[t] - lse;
  }
}

extern "C" void kernel_launch(void* const* d_in, const int* in_sizes, int n_in,
                              void* d_out, int out_size, void* d_ws, size_t ws_size,
                              hipStream_t stream) {
  const float* x     = (const float*)d_in[0];
  const int*   ei    = (const int*)  d_in[1];
  const int*   batch = (const int*)  d_in[2];
  const float* Wl[3]  = {(const float*)d_in[3],  (const float*)d_in[9],  (const float*)d_in[15]};
  const float* bl[3]  = {(const float*)d_in[4],  (const float*)d_in[10], (const float*)d_in[16]};
  const float* Wr[3]  = {(const float*)d_in[5],  (const float*)d_in[11], (const float*)d_in[17]};
  const float* br[3]  = {(const float*)d_in[6],  (const float*)d_in[12], (const float*)d_in[18]};
  const float* att[3] = {(const float*)d_in[7],  (const float*)d_in[13], (const float*)d_in[19]};
  const float* bo[3]  = {(const float*)d_in[8],  (const float*)d_in[14], (const float*)d_in[20]};
  const float* fc1W = (const float*)d_in[21];
  const float* fc1b = (const float*)d_in[22];
  const float* fc2W = (const float*)d_in[23];
  const float* fc2b = (const float*)d_in[24];

  const int N  = in_sizes[2];
  const int E  = in_sizes[1]/2;
  const int Et = E + N;
  const int G  = out_size/2;
  const int NB = (N + 255)/256;            // scan blocks (<=512)
  const int NBUK = (N + (1<<BUKSH)-1) >> BUKSH;   // dst buckets (<=512)
  const int NEB = (Et + 4095)/4096;        // edge blocks for bucket kernels

  char* p = (char*)d_ws;
  auto alloc = [&](size_t bytes)->void*{
    void* r = (void*)p; p += (bytes + 255) & ~(size_t)255; return r;
  };
  int*      deg     = (int*)     alloc((size_t)N*4);
  int*      row_ptr = (int*)     alloc((size_t)(N+1)*4);
  int*      bsum    = (int*)     alloc((size_t)520*4);
  int*      bhist   = (int*)     alloc((size_t)(MAXBUK+1)*4);
  int*      bbase   = (int*)     alloc((size_t)(MAXBUK+1)*4);
  int*      bnext   = (int*)     alloc((size_t)(MAXBUK+1)*4);
  int*      dhist   = (int*)     alloc((size_t)520*4);
  int*      perm    = (int*)     alloc((size_t)N*4);
  int*      csr     = (int*)     alloc((size_t)Et*4);
  unsigned* ebuf    = (unsigned*)alloc((size_t)Et*4);
  __half*   xl      = (__half*)  alloc((size_t)N*H*2);
  __half*   xr      = (__half*)  alloc((size_t)N*H*2);
  __half*   hbuf    = (__half*)  alloc((size_t)N*H*2);
  _Float16* Wt      = (_Float16*)alloc((size_t)2*256*H*2);

  (void)hipMemsetAsync(bhist, 0, (size_t)(MAXBUK+1)*4, stream);
  (void)hipMemsetAsync(dhist, 0, (size_t)520*4, stream);
  k_prep<<<256, 256, 0, stream>>>(Wl[1], Wr[1], Wl[2], Wr[2], Wt);

  // ---- bucketed CSR build ----
  k_bhist   <<<NEB, 512, 0, stream>>>(ei, E, Et, NBUK, bhist);
  k_scan512 <<<1, 512, 0, stream>>>(bhist, NBUK, bbase, bnext);
  k_bscatter<<<NEB, 512, 0, stream>>>(ei, E, Et, NBUK, bnext, ebuf);
  k_bdeg    <<<NBUK, 256, 0, stream>>>(ebuf, bbase, N, deg);
  k_scanA   <<<NB, 256, 0, stream>>>(deg, N, bsum);
  k_scan512 <<<1, 512, 0, stream>>>(bsum, NB, bsum, nullptr);
  k_scanC   <<<NB, 256, 0, stream>>>(deg, bsum, N, Et, row_ptr);
  k_bcsr    <<<NBUK, 256, 0, stream>>>(ebuf, bbase, row_ptr, csr);
  // ---- degree-bucket counting sort -> perm ----
  k_dhist   <<<NB, 256, 0, stream>>>(deg, N, dhist);
  k_scan512 <<<1, 512, 0, stream>>>(dhist, 256, dhist, nullptr);
  k_dscatter<<<NB, 256, 0, stream>>>(deg, N, dhist, perm);

  const int g7  = (N + 7)/8;
  const int gM  = (N + 63)/64;
  const int gg  = (int)(((size_t)N*16 + 255)/256);

  // layer 0 (K=7)
  k_gemm7<<<g7, 128, 0, stream>>>(x, Wl[0], bl[0], Wr[0], br[0], xl, xr, N);
  k_gat<<<gg, 256, 0, stream>>>(xl, xr, att[0], bo[0], row_ptr, csr, perm, hbuf, N);
  // layer 1
  k_gemm2h<<<gM, 256, 0, stream>>>(hbuf, Wt, bl[1], br[1], xl, xr, N);
  k_gat<<<gg, 256, 0, stream>>>(xl, xr, att[1], bo[1], row_ptr, csr, perm, hbuf, N);
  // layer 2
  k_gemm2h<<<gM, 256, 0, stream>>>(hbuf, Wt + (size_t)256*H, bl[2], br[2], xl, xr, N);
  k_gat<<<gg, 256, 0, stream>>>(xl, xr, att[2], bo[2], row_ptr, csr, perm, hbuf, N);

  // fused pool + head (sorted batch, no atomics)
  k_fc<<<G, 256, 0, stream>>>(hbuf, batch, N, fc1W, fc1b, fc2W, fc2b, (float*)d_out);
}

// Round 9
// 517.396 us; speedup vs baseline: 2.8226x; 1.1122x over previous
//
#include <hip/hip_runtime.h>
#include <hip/hip_fp16.h>
#include <math.h>

#define H 128
#define FCD 256
#define BUKSH 7                    // 128 dst nodes per bucket
#define MAXBUK 512                 // supports N <= 65536

typedef _Float16 half8 __attribute__((ext_vector_type(8)));
typedef float floatx4 __attribute__((ext_vector_type(4)));

// ---------------- DPP 16-lane (row) reduction: 4 VALU adds, no LDS pipe -------
template<int CTRL>
__device__ __forceinline__ float dppadd(float x){
  return x + __int_as_float(__builtin_amdgcn_update_dpp(
      0, __float_as_int(x), CTRL, 0xf, 0xf, true));
}
__device__ __forceinline__ float grp16_sum(float x){
  x = dppadd<0x128>(x);   // row_ror:8
  x = dppadd<0x124>(x);   // row_ror:4
  x = dppadd<0x122>(x);   // row_ror:2
  x = dppadd<0x121>(x);   // row_ror:1
  return x;
}

// ---------------- generic single-block exclusive scan (nb <= 512) -------------
__global__ void k_scan512(const int* __restrict__ in, int nb,
                          int* __restrict__ out1, int* __restrict__ out2){
  int t = threadIdx.x, lane = t & 63, w = t >> 6;
  int v = (t<nb) ? in[t] : 0;
  int x = v;
  #pragma unroll
  for (int off=1; off<64; off<<=1){
    int y = __shfl_up(x, off);
    if (lane >= off) x += y;
  }
  __shared__ int ws[8];
  if (lane==63) ws[w] = x;
  __syncthreads();
  int wo = 0;
  #pragma unroll
  for (int i=0;i<8;i++) if (i<w) wo += ws[i];
  int excl = wo + x - v;
  if (t<nb){ out1[t] = excl; if (out2) out2[t] = excl; }
  if (t==511) out1[nb] = wo + x;
}

// ---------------- bucketed CSR build ----------------
__global__ void k_bhist(const int* __restrict__ ei, int E, int Et, int nbuk,
                        int* __restrict__ bhist){
  __shared__ int lh[MAXBUK];
  int t = threadIdx.x;
  lh[t] = 0;
  __syncthreads();
  int j0 = blockIdx.x*4096;
  #pragma unroll
  for (int i=0;i<8;i++){
    int j = j0 + i*512 + t;
    if (j < Et){
      int dst = (j < E) ? ei[E+j] : (j - E);
      atomicAdd(&lh[dst>>BUKSH], 1);
    }
  }
  __syncthreads();
  if (t < nbuk && lh[t]) atomicAdd(&bhist[t], lh[t]);
}

__global__ void k_bscatter(const int* __restrict__ ei, int E, int Et, int nbuk,
                           int* __restrict__ bnext, unsigned* __restrict__ ebuf){
  __shared__ int lh[MAXBUK];
  __shared__ int lbase[MAXBUK];
  int t = threadIdx.x;
  lh[t] = 0;
  __syncthreads();
  int j0 = blockIdx.x*4096;
  unsigned pk[8]; int bk[8]; int rk[8];
  #pragma unroll
  for (int i=0;i<8;i++){
    int j = j0 + i*512 + t;
    if (j < Et){
      int src, dst;
      if (j < E){ src = ei[j]; dst = ei[E+j]; } else { src = dst = j - E; }
      pk[i] = (unsigned)src | ((unsigned)dst << 16);
      bk[i] = dst >> BUKSH;
      rk[i] = atomicAdd(&lh[bk[i]], 1);
    }
  }
  __syncthreads();
  if (t < nbuk){
    int c = lh[t];
    lbase[t] = c ? atomicAdd(&bnext[t], c) : 0;
  }
  __syncthreads();
  #pragma unroll
  for (int i=0;i<8;i++){
    int j = j0 + i*512 + t;
    if (j < Et) ebuf[lbase[bk[i]] + rk[i]] = pk[i];
  }
}

__global__ void k_bdeg(const unsigned* __restrict__ ebuf, const int* __restrict__ bbase,
                       int N, int* __restrict__ deg){
  __shared__ int cnt[1<<BUKSH];
  int b = blockIdx.x, t = threadIdx.x;
  if (t < (1<<BUKSH)) cnt[t] = 0;
  __syncthreads();
  int lo = bbase[b], hi = bbase[b+1];
  for (int j = lo + t; j < hi; j += 256){
    unsigned d = ebuf[j] >> 16;
    atomicAdd(&cnt[d & ((1<<BUKSH)-1)], 1);
  }
  __syncthreads();
  if (t < (1<<BUKSH)){
    int node = (b<<BUKSH) + t;
    if (node < N) deg[node] = cnt[t];
  }
}

__global__ void k_bcsr(const unsigned* __restrict__ ebuf, const int* __restrict__ bbase,
                       const int* __restrict__ row_ptr, int* __restrict__ csr){
  __shared__ int lnxt[1<<BUKSH];
  int b = blockIdx.x, t = threadIdx.x;
  if (t < (1<<BUKSH)) lnxt[t] = 0;
  __syncthreads();
  int lo = bbase[b], hi = bbase[b+1];
  for (int j = lo + t; j < hi; j += 256){
    unsigned e = ebuf[j];
    int dst = e >> 16, src = e & 0xffff;
    int r = atomicAdd(&lnxt[dst & ((1<<BUKSH)-1)], 1);
    csr[row_ptr[dst] + r] = src;
  }
}

// ---------------- row_ptr scan over deg ----------------
__global__ void k_scanA(const int* __restrict__ deg, int N, int* __restrict__ bsum){
  int t = threadIdx.x, lane = t & 63, w = t >> 6;
  int i = blockIdx.x*256 + t;
  int v = (i<N) ? deg[i] : 0;
  #pragma unroll
  for (int off=32; off; off>>=1) v += __shfl_xor(v, off);
  __shared__ int ws[4];
  if (lane==0) ws[w] = v;
  __syncthreads();
  if (t==0) bsum[blockIdx.x] = ws[0]+ws[1]+ws[2]+ws[3];
}

// row_ptr[N]=total written by thread (0,0) (R8 fix).
__global__ void k_scanC(const int* __restrict__ deg, const int* __restrict__ bsum, int N,
                        int total, int* __restrict__ row_ptr){
  int t = threadIdx.x, lane = t & 63, w = t >> 6;
  if (blockIdx.x==0 && t==0) row_ptr[N] = total;
  int i = blockIdx.x*256 + t;
  int v = (i<N) ? deg[i] : 0;
  int x = v;
  #pragma unroll
  for (int off=1; off<64; off<<=1){
    int y = __shfl_up(x, off);
    if (lane >= off) x += y;
  }
  __shared__ int ws[4];
  if (lane==63) ws[w] = x;
  __syncthreads();
  int woff = (w>0?ws[0]:0) + (w>1?ws[1]:0) + (w>2?ws[2]:0);
  int excl = bsum[blockIdx.x] + woff + x - v;
  if (i<N) row_ptr[i] = excl;
}

// ------- degree sort, zero global atomics (R9): 2-level histogram ranks -------
// phase 1: per-block LDS histogram -> plain writes hists[b][256]
__global__ void k_dhistM(const int* __restrict__ deg, int N, int* __restrict__ hists){
  __shared__ int lh[256];
  int t = threadIdx.x, b = blockIdx.x;
  lh[t] = 0;
  __syncthreads();
  int i = b*256 + t;
  if (i < N) atomicAdd(&lh[min(deg[i],255)], 1);
  __syncthreads();
  hists[b*256 + t] = lh[t];
}

// phase 2: column-wise exclusive scan over blocks (thread d owns bin d;
// reads/writes coalesced across threads), bin totals out.
__global__ void k_dcolscan(int* __restrict__ hists, int nb, int* __restrict__ bintot){
  int d = threadIdx.x;
  int run = 0;
  for (int b=0; b<nb; b++){
    int v = hists[b*256 + d];
    hists[b*256 + d] = run;
    run += v;
  }
  bintot[d] = run;
}

// phase 4: block-local LDS ranks + precomputed offsets -> perm (stable-ish)
__global__ void k_dscatter2(const int* __restrict__ deg, int N,
                            const int* __restrict__ hists, const int* __restrict__ base,
                            int* __restrict__ perm){
  __shared__ int lh[256];
  int t = threadIdx.x, b = blockIdx.x;
  lh[t] = 0;
  __syncthreads();
  int i = b*256 + t;
  int d = 0, r = 0;
  if (i < N){ d = min(deg[i],255); r = atomicAdd(&lh[d], 1); }
  if (i < N) perm[base[d] + hists[b*256 + d] + r] = i;
}

// ------------- weight prep: Wl/Wr (128x128 f32, k-major) -> Wt fp16 [L][n][k] --
__global__ void k_prep(const float* __restrict__ Wl1, const float* __restrict__ Wr1,
                       const float* __restrict__ Wl2, const float* __restrict__ Wr2,
                       _Float16* __restrict__ Wt){
  int idx = blockIdx.x*256 + threadIdx.x;   // 2*256*128 = 65536 total
  int L   = idx >> 15;
  int rem = idx & 32767;
  int nn  = rem >> 7;        // 0..255
  int k   = rem & 127;
  const float* W = (L==0) ? (nn<H?Wl1:Wr1) : (nn<H?Wl2:Wr2);
  Wt[idx] = (_Float16)W[k*H + (nn&127)];
}

// ---------------- layer-0 K=7 GEMM pair: x fp32 -> xl/xr fp16 ----------------
__global__ void k_gemm7(const float* __restrict__ x,
                        const float* __restrict__ Wl, const float* __restrict__ bl,
                        const float* __restrict__ Wr, const float* __restrict__ br,
                        __half* __restrict__ xl, __half* __restrict__ xr, int n){
  int col = threadIdx.x;            // 0..127
  int n0 = blockIdx.x*8;
  float accl[8], accr[8];
  float bL = bl[col], bR = br[col];
  #pragma unroll
  for (int t=0;t<8;t++){ accl[t]=bL; accr[t]=bR; }
  #pragma unroll
  for (int k=0;k<7;k++){
    float wl = Wl[k*H + col];
    float wr = Wr[k*H + col];
    #pragma unroll
    for (int t=0;t<8;t++){
      int node = n0+t; if (node >= n) node = n-1;
      float hv = x[(size_t)node*7 + k];
      accl[t] = fmaf(hv, wl, accl[t]);
      accr[t] = fmaf(hv, wr, accr[t]);
    }
  }
  #pragma unroll
  for (int t=0;t<8;t++){
    int node = n0+t;
    if (node < n){
      xl[(size_t)node*H + col] = __float2half(accl[t]);
      xr[(size_t)node*H + col] = __float2half(accr[t]);
    }
  }
}

// ------------- MFMA GEMM pair: h[n,128]f16 @ Wt -> xl,xr f16 (f32 accum) ------
__global__ __launch_bounds__(256) void k_gemm2h(
    const __half* __restrict__ h, const _Float16* __restrict__ Wt,
    const float* __restrict__ bl, const float* __restrict__ br,
    __half* __restrict__ xl, __half* __restrict__ xr, int n){
  int wave = threadIdx.x >> 6, lane = threadIdx.x & 63;
  int m16 = lane & 15, quad = lane >> 4;
  int row0 = blockIdx.x*64 + wave*16;
  int arow = row0 + m16; if (arow >= n) arow = n-1;
  const __half* hr = h + (size_t)arow*H;
  half8 a[4];
  #pragma unroll
  for (int kb=0;kb<4;kb++) a[kb] = *(const half8*)(hr + kb*32 + quad*8);
  floatx4 acc[16];
  #pragma unroll
  for (int t=0;t<16;t++){ floatx4 z = {0.f,0.f,0.f,0.f}; acc[t] = z; }
  #pragma unroll
  for (int nt=0;nt<16;nt++){
    const _Float16* wr_ = Wt + (size_t)(nt*16 + m16)*H;
    #pragma unroll
    for (int kb=0;kb<4;kb++){
      half8 b = *(const half8*)(wr_ + kb*32 + quad*8);
      acc[nt] = __builtin_amdgcn_mfma_f32_16x16x32_f16(a[kb], b, acc[nt], 0,0,0);
    }
  }
  #pragma unroll
  for (int nt=0;nt<16;nt++){
    int c = nt*16 + m16;                 // D col = lane&15
    float bias; __half* dst; int cc;
    if (c < H){ bias = bl[c];   dst = xl; cc = c;   }
    else      { bias = br[c-H]; dst = xr; cc = c-H; }
    #pragma unroll
    for (int r=0;r<4;r++){
      int rw = row0 + quad*4 + r;        // D row = quad*4 + r
      if (rw < n) dst[(size_t)rw*H + cc] = __float2half(acc[nt][r] + bias);
    }
  }
}

// ------------- GATv2: 16 lanes/node, 8 feats/lane, unroll-8, fp32 edge math ---
__global__ void k_gat(const __half* __restrict__ xl, const __half* __restrict__ xr,
                      const float* __restrict__ att, const float* __restrict__ bo,
                      const int* __restrict__ row_ptr, const int* __restrict__ csr_src,
                      const int* __restrict__ perm,
                      __half* __restrict__ hout, int n){
  int gid0 = (int)((blockIdx.x*blockDim.x + threadIdx.x) >> 4);
  int lane16 = threadIdx.x & 15;
  if (gid0 >= n) return;
  int gid = perm[gid0];                  // degree-sorted order
  int f = lane16*8;
  float xrv[8], av[8];
  {
    union { float4 q; __half2 h[4]; } U;
    U.q = *(const float4*)(xr + (size_t)gid*H + f);
    #pragma unroll
    for (int i=0;i<4;i++){ float2 t2 = __half22float2(U.h[i]); xrv[2*i]=t2.x; xrv[2*i+1]=t2.y; }
    float4 a0 = *(const float4*)(att + f);
    float4 a1 = *(const float4*)(att + f + 4);
    av[0]=a0.x; av[1]=a0.y; av[2]=a0.z; av[3]=a0.w;
    av[4]=a1.x; av[5]=a1.y; av[6]=a1.z; av[7]=a1.w;
  }
  float acc[8];
  #pragma unroll
  for (int i=0;i<8;i++) acc[i]=0.f;
  float mmax = -INFINITY, denom = 0.f;
  int beg = row_ptr[gid], end = row_ptr[gid+1];
  int j = beg;
  for (; j+7 < end; j += 8){
    int s[8];
    #pragma unroll
    for (int u=0;u<8;u++) s[u] = csr_src[j+u];
    float4 r[8];
    #pragma unroll
    for (int u=0;u<8;u++) r[u] = *(const float4*)(xl + (size_t)s[u]*H + f);
    float d[8];
    #pragma unroll
    for (int u=0;u<8;u++){
      union { float4 q; __half2 h[4]; } U; U.q = r[u];
      float dd = 0.f;
      #pragma unroll
      for (int i=0;i<4;i++){
        float2 vf = __half22float2(U.h[i]);
        float u0 = vf.x + xrv[2*i];
        float u1 = vf.y + xrv[2*i+1];
        float l0 = fmaf(0.4f, fabsf(u0), 0.6f*u0);   // leaky_relu(u,0.2)
        float l1 = fmaf(0.4f, fabsf(u1), 0.6f*u1);
        dd = fmaf(l0, av[2*i], fmaf(l1, av[2*i+1], dd));
      }
      d[u] = dd;
    }
    #pragma unroll
    for (int u=0;u<8;u++) d[u] = grp16_sum(d[u]);
    float m8 = fmaxf(fmaxf(fmaxf(d[0],d[1]), fmaxf(d[2],d[3])),
                     fmaxf(fmaxf(d[4],d[5]), fmaxf(d[6],d[7])));
    if (m8 > mmax){
      float sc = __expf(mmax - m8);
      #pragma unroll
      for (int i=0;i<8;i++) acc[i] *= sc;
      denom *= sc;
      mmax = m8;
    }
    #pragma unroll
    for (int u=0;u<8;u++){
      float w = __expf(d[u] - mmax);
      denom += w;
      union { float4 q; __half2 h[4]; } U; U.q = r[u];
      #pragma unroll
      for (int i=0;i<4;i++){
        float2 vf = __half22float2(U.h[i]);
        acc[2*i]   = fmaf(w, vf.x, acc[2*i]);
        acc[2*i+1] = fmaf(w, vf.y, acc[2*i+1]);
      }
    }
  }
  for (; j<end; j++){
    int s0 = csr_src[j];
    union { float4 q; __half2 h[4]; } U;
    U.q = *(const float4*)(xl + (size_t)s0*H + f);
    float v0[8];
    #pragma unroll
    for (int i=0;i<4;i++){ float2 t0 = __half22float2(U.h[i]); v0[2*i]=t0.x; v0[2*i+1]=t0.y; }
    float dd = 0.f;
    #pragma unroll
    for (int i=0;i<8;i++){
      float u0 = v0[i] + xrv[i];
      float l0 = fmaf(0.4f, fabsf(u0), 0.6f*u0);
      dd = fmaf(l0, av[i], dd);
    }
    dd = grp16_sum(dd);
    if (dd > mmax){
      float sc = __expf(mmax - dd);
      #pragma unroll
      for (int i=0;i<8;i++) acc[i] *= sc;
      denom *= sc;
      mmax = dd;
    }
    float w = __expf(dd - mmax);
    denom += w;
    #pragma unroll
    for (int i=0;i<8;i++) acc[i] = fmaf(w, v0[i], acc[i]);
  }
  float inv = 1.f/denom;
  float o[8];
  {
    float4 b0 = *(const float4*)(bo + f);
    float4 b1 = *(const float4*)(bo + f + 4);
    float bb[8] = {b0.x,b0.y,b0.z,b0.w,b1.x,b1.y,b1.z,b1.w};
    #pragma unroll
    for (int i=0;i<8;i++){
      float t = acc[i]*inv + bb[i];
      o[i] = t > 0.f ? t : expm1f(t);   // ELU
    }
  }
  union { float4 f4; __half2 h2[4]; } u;
  #pragma unroll
  for (int i=0;i<4;i++) u.h2[i] = __floats2half2_rn(o[2*i], o[2*i+1]);
  *(float4*)(hout + (size_t)gid*H + f) = u.f4;
}

// --------- fused segment mean-pool (sorted batch, binary search) + MLP head ---
__global__ void k_fc(const __half* __restrict__ hbuf, const int* __restrict__ batch, int N,
                     const float* __restrict__ W1, const float* __restrict__ b1,
                     const float* __restrict__ W2, const float* __restrict__ b2,
                     float* __restrict__ out){
  __shared__ float g[H];
  __shared__ float2 part[4][64];
  __shared__ float zs[FCD];
  __shared__ int bounds[2];
  int gi = blockIdx.x;
  int t = threadIdx.x;     // 0..255
  if (t < 2){
    int target = gi + t;
    int lo = 0, hi = N;
    while (lo < hi){ int mid = (lo+hi)>>1; if (batch[mid] < target) lo = mid+1; else hi = mid; }
    bounds[t] = lo;
  }
  __syncthreads();
  int lo = bounds[0], hi = bounds[1];
  int pairc = t & 63, slice = t >> 6;
  float sx = 0.f, sy = 0.f;
  for (int node = lo + slice; node < hi; node += 4){
    float2 f2 = __half22float2(*(const __half2*)(hbuf + (size_t)node*H + pairc*2));
    sx += f2.x; sy += f2.y;
  }
  part[slice][pairc] = make_float2(sx, sy);
  __syncthreads();
  if (t < 64){
    float2 a = part[0][t], b = part[1][t], c = part[2][t], d = part[3][t];
    float cnt = (float)(hi - lo); if (cnt < 1.f) cnt = 1.f;
    float inv = 1.f/cnt;
    g[2*t]   = (a.x+b.x+c.x+d.x)*inv;
    g[2*t+1] = (a.y+b.y+c.y+d.y)*inv;
  }
  __syncthreads();
  float acc = b1[t];
  for (int k=0;k<H;k++) acc = fmaf(g[k], W1[k*FCD+t], acc);
  zs[t] = acc > 0.f ? acc : 0.f;
  __syncthreads();
  if (t < 2){
    float l = b2[t];
    for (int k=0;k<FCD;k++) l = fmaf(zs[k], W2[k*2+t], l);
    g[t] = l;
  }
  __syncthreads();
  if (t < 2){
    float l0 = g[0], l1 = g[1];
    float mx = fmaxf(l0,l1);
    float lse = mx + logf(__expf(l0-mx) + __expf(l1-mx));
    out[gi*2+t] = g[t] - lse;
  }
}

extern "C" void kernel_launch(void* const* d_in, const int* in_sizes, int n_in,
                              void* d_out, int out_size, void* d_ws, size_t ws_size,
                              hipStream_t stream) {
  const float* x     = (const float*)d_in[0];
  const int*   ei    = (const int*)  d_in[1];
  const int*   batch = (const int*)  d_in[2];
  const float* Wl[3]  = {(const float*)d_in[3],  (const float*)d_in[9],  (const float*)d_in[15]};
  const float* bl[3]  = {(const float*)d_in[4],  (const float*)d_in[10], (const float*)d_in[16]};
  const float* Wr[3]  = {(const float*)d_in[5],  (const float*)d_in[11], (const float*)d_in[17]};
  const float* br[3]  = {(const float*)d_in[6],  (const float*)d_in[12], (const float*)d_in[18]};
  const float* att[3] = {(const float*)d_in[7],  (const float*)d_in[13], (const float*)d_in[19]};
  const float* bo[3]  = {(const float*)d_in[8],  (const float*)d_in[14], (const float*)d_in[20]};
  const float* fc1W = (const float*)d_in[21];
  const float* fc1b = (const float*)d_in[22];
  const float* fc2W = (const float*)d_in[23];
  const float* fc2b = (const float*)d_in[24];

  const int N  = in_sizes[2];
  const int E  = in_sizes[1]/2;
  const int Et = E + N;
  const int G  = out_size/2;
  const int NB = (N + 255)/256;            // scan blocks (<=512)
  const int NBUK = (N + (1<<BUKSH)-1) >> BUKSH;   // dst buckets (<=512)
  const int NEB = (Et + 4095)/4096;        // edge blocks for bucket kernels

  char* p = (char*)d_ws;
  auto alloc = [&](size_t bytes)->void*{
    void* r = (void*)p; p += (bytes + 255) & ~(size_t)255; return r;
  };
  int*      deg     = (int*)     alloc((size_t)N*4);
  int*      row_ptr = (int*)     alloc((size_t)(N+1)*4);
  int*      bsum    = (int*)     alloc((size_t)520*4);
  int*      bhist   = (int*)     alloc((size_t)(MAXBUK+1)*4);
  int*      bbase   = (int*)     alloc((size_t)(MAXBUK+1)*4);
  int*      bnext   = (int*)     alloc((size_t)(MAXBUK+1)*4);
  int*      hists   = (int*)     alloc((size_t)512*256*4);
  int*      bintot  = (int*)     alloc((size_t)260*4);
  int*      dbase   = (int*)     alloc((size_t)260*4);
  int*      perm    = (int*)     alloc((size_t)N*4);
  int*      csr     = (int*)     alloc((size_t)Et*4);
  unsigned* ebuf    = (unsigned*)alloc((size_t)Et*4);
  __half*   xl      = (__half*)  alloc((size_t)N*H*2);
  __half*   xr      = (__half*)  alloc((size_t)N*H*2);
  __half*   hbuf    = (__half*)  alloc((size_t)N*H*2);
  _Float16* Wt      = (_Float16*)alloc((size_t)2*256*H*2);

  (void)hipMemsetAsync(bhist, 0, (size_t)(MAXBUK+1)*4, stream);
  k_prep<<<256, 256, 0, stream>>>(Wl[1], Wr[1], Wl[2], Wr[2], Wt);

  // ---- bucketed CSR build ----
  k_bhist   <<<NEB, 512, 0, stream>>>(ei, E, Et, NBUK, bhist);
  k_scan512 <<<1, 512, 0, stream>>>(bhist, NBUK, bbase, bnext);
  k_bscatter<<<NEB, 512, 0, stream>>>(ei, E, Et, NBUK, bnext, ebuf);
  k_bdeg    <<<NBUK, 256, 0, stream>>>(ebuf, bbase, N, deg);
  k_scanA   <<<NB, 256, 0, stream>>>(deg, N, bsum);
  k_scan512 <<<1, 512, 0, stream>>>(bsum, NB, bsum, nullptr);
  k_scanC   <<<NB, 256, 0, stream>>>(deg, bsum, N, Et, row_ptr);
  k_bcsr    <<<NBUK, 256, 0, stream>>>(ebuf, bbase, row_ptr, csr);
  // ---- degree sort -> perm (zero global atomics) ----
  k_dhistM  <<<NB, 256, 0, stream>>>(deg, N, hists);
  k_dcolscan<<<1, 256, 0, stream>>>(hists, NB, bintot);
  k_scan512 <<<1, 512, 0, stream>>>(bintot, 256, dbase, nullptr);
  k_dscatter2<<<NB, 256, 0, stream>>>(deg, N, hists, dbase, perm);

  const int g7  = (N + 7)/8;
  const int gM  = (N + 63)/64;
  const int gg  = (int)(((size_t)N*16 + 255)/256);

  // layer 0 (K=7)
  k_gemm7<<<g7, 128, 0, stream>>>(x, Wl[0], bl[0], Wr[0], br[0], xl, xr, N);
  k_gat<<<gg, 256, 0, stream>>>(xl, xr, att[0], bo[0], row_ptr, csr, perm, hbuf, N);
  // layer 1
  k_gemm2h<<<gM, 256, 0, stream>>>(hbuf, Wt, bl[1], br[1], xl, xr, N);
  k_gat<<<gg, 256, 0, stream>>>(xl, xr, att[1], bo[1], row_ptr, csr, perm, hbuf, N);
  // layer 2
  k_gemm2h<<<gM, 256, 0, stream>>>(hbuf, Wt + (size_t)256*H, bl[2], br[2], xl, xr, N);
  k_gat<<<gg, 256, 0, stream>>>(xl, xr, att[2], bo[2], row_ptr, csr, perm, hbuf, N);

  // fused pool + head (sorted batch, no atomics)
  k_fc<<<G, 256, 0, stream>>>(hbuf, batch, N, fc1W, fc1b, fc2W, fc2b, (float*)d_out);
}